// Round 17
// baseline (248.221 us; speedup 1.0000x reference)
//
#include <hip/hip_runtime.h>
#include <math.h>

#define BB 4
#define CC 512
#define TT 2048
#define HH 8
#define DD 64

static constexpr float SCALE = 0.125f;                 // D^-0.5
static constexpr float QK_SCALE_LOG2 = 0.125f * 1.4426950408889634f;  // fold log2(e): softmax in exp2 domain

typedef __attribute__((ext_vector_type(8)))  short  short8;
typedef __attribute__((ext_vector_type(4)))  float  f32x4;
typedef __attribute__((ext_vector_type(16))) float  f32x16;
typedef __attribute__((ext_vector_type(2)))  unsigned int u32x2;

static __device__ __forceinline__ ushort f2bf(float f) {
    uint u = __float_as_uint(f);
    uint r = (u + 0x7fffu + ((u >> 16) & 1u)) >> 16;
    return (ushort)r;
}
static __device__ __forceinline__ float bf2f(ushort u) {
    return __uint_as_float((uint)u << 16);
}

typedef unsigned int u32;
typedef u32 __attribute__((address_space(1))) gu32;
typedef u32 __attribute__((address_space(3))) lu32;
static __device__ __forceinline__ void gload_lds16(const void* g, void* l) {
    __builtin_amdgcn_global_load_lds((const gu32*)g, (lu32*)l, 16, 0, 0);
}

// ======================= fused prep: rope table + weight cvt + input transpose =======================
__global__ __launch_bounds__(256)
void prep_kernel(const float* __restrict__ x, const float* __restrict__ cond,
                 const float* w0, const float* w1, const float* w2, const float* w3,
                 const float* w4, const float* w5, const float* w6, const float* w7,
                 ushort* __restrict__ wbf, ushort* __restrict__ wc,
                 ushort* __restrict__ xtb, ushort* __restrict__ ctb,
                 float* __restrict__ ctab, float* __restrict__ stab)
{
    __shared__ ushort L[64][66];
    int bid = blockIdx.x;
    const int tid = threadIdx.x;

    if (bid < 256) {                       // ---- rope table ----
        int idx = bid * 256 + tid;         // 64K threads: [i][t]
        int i = idx >> 11;
        int t = idx & 2047;
        float ex   = (2.0f * (float)i) / 64.0f;
        float invf = powf(10000.0f, -ex);
        float ang  = (float)t * invf;
        ctab[idx] = cosf(ang);
        stab[idx] = sinf(ang);
        return;
    }
    bid -= 256;
    if (bid < 2048) {                      // ---- weight fp32 -> bf16 ----
        const float* srcs[8] = {w0, w1, w2, w3, w4, w5, w6, w7};
        int wi = bid >> 8;
        int idx = ((bid & 255) * 256 + tid) * 4;
        float4 v = *(const float4*)&srcs[wi][idx];
        uint lo = (uint)f2bf(v.x) | ((uint)f2bf(v.y) << 16);
        uint hi = (uint)f2bf(v.z) | ((uint)f2bf(v.w) << 16);
        uint2 pk = make_uint2(lo, hi);
        if (wi < 6) {
            *(uint2*)&wbf[(size_t)wi * 262144 + idx] = pk;
        } else {
            int row = idx >> 9, col = idx & 511;
            *(uint2*)&wc[(size_t)row * 1024 + (wi - 6) * 512 + col] = pk;
        }
        return;
    }
    bid -= 2048;                           // ---- transpose [b][c][t] -> bf16 [b][t][c] ----
    const int z = bid >> 8;                // 0..7
    const int r = bid & 255;
    const float* in = (z < 4) ? x : cond;
    ushort* outp    = (z < 4) ? xtb : ctb;
    const int b = z & 3;
    const int t0 = (r & 31) * 64, c0 = (r >> 5) * 64;
    const float* inb = in + (size_t)b * CC * TT;
    ushort* outb = outp + (size_t)b * TT * CC;
    const int lc = tid >> 6;
    const int lt = tid & 63;
    #pragma unroll
    for (int i = 0; i < 16; i++) {
        int c = i * 4 + lc;
        L[c][lt] = f2bf(inb[(size_t)(c0 + c) * TT + t0 + lt]);
    }
    __syncthreads();
    #pragma unroll
    for (int i = 0; i < 16; i++) {
        int t = i * 4 + lc;
        outb[(size_t)(t0 + t) * CC + c0 + lt] = L[lt][t];
    }
}

// ---- scrambled local-attn output [b][c][t] -> AG[b][t][0..512) (row stride 1024) ----
__global__ __launch_bounds__(256)
void transpose_bf16_kernel(const ushort* __restrict__ in, ushort* __restrict__ AG)
{
    __shared__ ushort L[64][66];
    const int t0 = blockIdx.x * 64, c0 = blockIdx.y * 64, b = blockIdx.z;
    const ushort* inb = in + (size_t)b * CC * TT;
    ushort* outb = AG + (size_t)b * TT * 1024;
    const int lc = threadIdx.x >> 6;
    const int lt = threadIdx.x & 63;
    #pragma unroll
    for (int i = 0; i < 16; i++) {
        int c = i * 4 + lc;
        L[c][lt] = inb[(size_t)(c0 + c) * TT + t0 + lt];
    }
    __syncthreads();
    #pragma unroll
    for (int i = 0; i < 16; i++) {
        int t = i * 4 + lc;
        outb[(size_t)(t0 + t) * 1024 + c0 + lt] = L[lt][t];
    }
}

// ======================= MFMA GEMM core (macro used by gemm_comb only) =======================
#define GEMM_BODY(Wp, XTp, KD, NB)                                                  \
    __shared__ __align__(16) ushort As[2][128][32];                                 \
    __shared__ __align__(16) ushort Bs[2][NB][32];                                  \
    const int tid  = threadIdx.x;                                                   \
    const int wid  = tid >> 6;                                                      \
    const int lane = tid & 63;                                                      \
    const int x  = lane & 15;                                                       \
    const int gq = lane >> 4;                                                       \
    const int wm = wid >> 1, wn = wid & 1;                                          \
    const int m0 = blockIdx.y * 128;                                                \
    const int n0 = blockIdx.x * NB;                                                 \
    const int srow = lane >> 2;                                                     \
    const int sblk = lane & 3;                                                      \
    f32x4 acc[4][NB / 32];                                                          \
    _Pragma("unroll")                                                               \
    for (int i = 0; i < 4; i++)                                                     \
        _Pragma("unroll")                                                           \
        for (int j = 0; j < NB / 32; j++) acc[i][j] = (f32x4){0.f, 0.f, 0.f, 0.f};  \
    auto stage = [&](int bf, int k0) {                                              \
        _Pragma("unroll")                                                           \
        for (int c = 0; c < 2; c++) {                                               \
            int row = c * 64 + wid * 16 + srow;                                     \
            int dbk = sblk ^ ((row >> 1) & 3);                                      \
            gload_lds16(&Wp[(size_t)(m0 + row) * KD + k0 + dbk * 8],                \
                        &As[bf][c * 64 + wid * 16][0]);                             \
            if (c * 64 < NB)                                                        \
                gload_lds16(&XTp[(size_t)(n0 + row) * KD + k0 + dbk * 8],           \
                            &Bs[bf][c * 64 + wid * 16][0]);                         \
        }                                                                           \
    };                                                                              \
    stage(0, 0);                                                                    \
    __syncthreads();                                                                \
    for (int ks = 0; ks < (KD) / 32; ks++) {                                        \
        int cur = ks & 1;                                                           \
        if (ks < (KD) / 32 - 1) stage(cur ^ 1, (ks + 1) * 32);                      \
        short8 aF[4], bF[NB / 32];                                                  \
        _Pragma("unroll")                                                           \
        for (int mi = 0; mi < 4; mi++) {                                            \
            int row = wm * 64 + mi * 16 + x;                                        \
            aF[mi] = *(const short8*)&As[cur][row][(gq ^ ((row >> 1) & 3)) * 8];    \
        }                                                                           \
        _Pragma("unroll")                                                           \
        for (int nj = 0; nj < NB / 32; nj++) {                                      \
            int row = wn * (NB / 2) + nj * 16 + x;                                  \
            bF[nj] = *(const short8*)&Bs[cur][row][(gq ^ ((row >> 1) & 3)) * 8];    \
        }                                                                           \
        _Pragma("unroll")                                                           \
        for (int mi = 0; mi < 4; mi++)                                              \
            _Pragma("unroll")                                                       \
            for (int nj = 0; nj < NB / 32; nj++)                                    \
                acc[mi][nj] = __builtin_amdgcn_mfma_f32_16x16x32_bf16(aF[mi], bF[nj], acc[mi][nj], 0, 0, 0); \
        __syncthreads();                                                            \
    }

// ---- all 6 qkv projections, 8-WAVE blocks (wave grid 2m x 4n; 64x32 per wave) ----
// z0:lq z1:lk z2:lv (bf16 C^T [t][c]) | z3:gq (C^T, rope, qscale)
// z4:gk (rope, fragment-tiled KT) | z5:gv (fragment-tiled VT, operand-swapped k-loop)
// acc = 8 f32x4/wave (32 VGPR) -> ~6 waves/SIMD; LDS unchanged 32KB dbuf.
__global__ __launch_bounds__(512, 6)
void gemm6_kernel(const ushort* __restrict__ wbase,
                  const float* __restrict__ b0, const float* __restrict__ b1, const float* __restrict__ b2,
                  const float* __restrict__ b3, const float* __restrict__ b4, const float* __restrict__ b5,
                  const ushort* __restrict__ xtb, const ushort* __restrict__ ctb,
                  ushort* __restrict__ y0, ushort* __restrict__ y1, ushort* __restrict__ y2,
                  ushort* __restrict__ y3, ushort* __restrict__ y4, ushort* __restrict__ y5,
                  const float* __restrict__ ctab, const float* __restrict__ stab)
{
    __shared__ __align__(16) ushort SMEM[16384];   // As[2][128][32] | Bs[2][128][32] | bounce(128x128)
    ushort (*As)[128][32] = (ushort(*)[128][32])&SMEM[0];
    ushort (*Bs)[128][32] = (ushort(*)[128][32])&SMEM[8192];

    const int z = blockIdx.z;
    const ushort* Wp  = wbase + (size_t)z * 262144;
    const float* bias = (z == 0) ? b0 : (z == 1) ? b1 : (z == 2) ? b2 : (z == 3) ? b3 : (z == 4) ? b4 : b5;
    const ushort* XTp = (z == 0 || z == 3) ? xtb : ctb;
    ushort* Y = (z == 0) ? y0 : (z == 1) ? y1 : (z == 2) ? y2 : (z == 3) ? y3 : (z == 4) ? y4 : y5;
    const bool do_rope = (z == 3 || z == 4);
    const bool swp = (z == 5);
    const float qscale = (z == 3) ? QK_SCALE_LOG2 : 1.0f;

    const int tid  = threadIdx.x;          // 0..511
    const int wid  = tid >> 6;             // 0..7
    const int lane = tid & 63;
    const int x  = lane & 15;
    const int gq = lane >> 4;
    const int wm = wid >> 2;               // 0..1 (64 m-rows each)
    const int wn = wid & 3;                // 0..3 (32 n-rows each)
    const int m0 = blockIdx.y * 128;
    const int n0 = blockIdx.x * 128;
    const int srow = lane >> 2;
    const int sblk = lane & 3;

    f32x4 acc[4][2];
    #pragma unroll
    for (int i = 0; i < 4; i++)
        #pragma unroll
        for (int j = 0; j < 2; j++) acc[i][j] = (f32x4){0.f, 0.f, 0.f, 0.f};

    // 512 threads cover 128 rows x 4 chunks per matrix: 1 gload A + 1 gload B each.
    auto stage = [&](int bf, int k0) {
        int row = wid * 16 + srow;                     // 0..127
        int dbk = sblk ^ ((row >> 1) & 3);
        gload_lds16(&Wp[(size_t)(m0 + row) * 512 + k0 + dbk * 8],
                    &As[bf][wid * 16][0]);
        gload_lds16(&XTp[(size_t)(n0 + row) * 512 + k0 + dbk * 8],
                    &Bs[bf][wid * 16][0]);
    };
    stage(0, 0);
    __syncthreads();

    for (int ks = 0; ks < 16; ks++) {
        int cur = ks & 1;
        if (ks < 15) stage(cur ^ 1, (ks + 1) * 32);
        short8 aF[4], bF[2];
        #pragma unroll
        for (int mi = 0; mi < 4; mi++) {
            int row = wm * 64 + mi * 16 + x;
            aF[mi] = *(const short8*)&As[cur][row][(gq ^ ((row >> 1) & 3)) * 8];
        }
        #pragma unroll
        for (int nj = 0; nj < 2; nj++) {
            int row = wn * 32 + nj * 16 + x;
            bF[nj] = *(const short8*)&Bs[cur][row][(gq ^ ((row >> 1) & 3)) * 8];
        }
        if (swp) {          // z5: D[n][m] — thread holds 4 consecutive t for fixed c
            #pragma unroll
            for (int mi = 0; mi < 4; mi++)
                #pragma unroll
                for (int nj = 0; nj < 2; nj++)
                    acc[mi][nj] = __builtin_amdgcn_mfma_f32_16x16x32_bf16(bF[nj], aF[mi], acc[mi][nj], 0, 0, 0);
        } else {            // D[m][n]
            #pragma unroll
            for (int mi = 0; mi < 4; mi++)
                #pragma unroll
                for (int nj = 0; nj < 2; nj++)
                    acc[mi][nj] = __builtin_amdgcn_mfma_f32_16x16x32_bf16(aF[mi], bF[nj], acc[mi][nj], 0, 0, 0);
        }
        __syncthreads();
    }

    // ---- bounce write: bias (+rope), pack 4 bf16 -> 8B into swizzled 128x128 tile ----
    if (!swp) {
        #pragma unroll
        for (int mi = 0; mi < 4; mi++) {
            const int cL = wm * 64 + mi * 16 + 4 * gq;
            const int mb = m0 + cL;
            float bv[4];
            #pragma unroll
            for (int r = 0; r < 4; r++) bv[r] = bias[mb + r];
            #pragma unroll
            for (int nj = 0; nj < 2; nj++) {
                const int tL = wn * 32 + nj * 16 + x;
                const int tt = (n0 + tL) & 2047;
                f32x4 v = acc[mi][nj];
                v[0] += bv[0]; v[1] += bv[1]; v[2] += bv[2]; v[3] += bv[3];
                if (do_rope) {
                    const int i0 = (mb & 63) >> 1;
                    float c0 = ctab[(size_t)i0 * 2048 + tt],       s0 = stab[(size_t)i0 * 2048 + tt];
                    float c1 = ctab[(size_t)(i0 + 1) * 2048 + tt], s1 = stab[(size_t)(i0 + 1) * 2048 + tt];
                    float e0 = (v[0] * c0 - v[1] * s0) * qscale;
                    float e1 = (v[0] * s0 + v[1] * c0) * qscale;
                    float e2 = (v[2] * c1 - v[3] * s1) * qscale;
                    float e3 = (v[2] * s1 + v[3] * c1) * qscale;
                    v[0] = e0; v[1] = e1; v[2] = e2; v[3] = e3;
                }
                uint lo = (uint)f2bf(v[0]) | ((uint)f2bf(v[1]) << 16);
                uint hi = (uint)f2bf(v[2]) | ((uint)f2bf(v[3]) << 16);
                const int blk = (cL >> 3) ^ (tL & 7);
                *(uint2*)&SMEM[tL * 128 + blk * 8 + (gq & 1) * 4] = make_uint2(lo, hi);
            }
        }
    } else {
        #pragma unroll
        for (int mi = 0; mi < 4; mi++) {
            const int cL = wm * 64 + mi * 16 + x;
            const float bv = bias[m0 + cL];
            #pragma unroll
            for (int nj = 0; nj < 2; nj++) {
                const int tL = wn * 32 + nj * 16 + 4 * gq;
                f32x4 v = acc[mi][nj];
                uint lo = (uint)f2bf(v[0] + bv) | ((uint)f2bf(v[1] + bv) << 16);
                uint hi = (uint)f2bf(v[2] + bv) | ((uint)f2bf(v[3] + bv) << 16);
                const int blk = (tL >> 3) ^ (cL & 7);
                *(uint2*)&SMEM[cL * 128 + blk * 8 + (gq & 1) * 4] = make_uint2(lo, hi);
            }
        }
    }
    __syncthreads();

    // ---- coalesced global stores (16B/thread, 4 sweeps of 512 threads) ----
    if (z <= 3) {
        #pragma unroll
        for (int s = 0; s < 4; s++) {
            const int chunk = s * 512 + tid;
            const int row = chunk >> 4;       // t
            const int blk = chunk & 15;       // c-block
            uint4 val = *(const uint4*)&SMEM[row * 128 + ((blk ^ (row & 7)) << 3)];
            *(uint4*)&Y[(size_t)(n0 + row) * 512 + m0 + blk * 8] = val;
        }
    } else if (z == 4) {
        const int bidx = n0 >> 11;
        #pragma unroll
        for (int s = 0; s < 4; s++) {
            const int chunk = s * 512 + tid;
            const int row = chunk & 127;      // t
            const int blk = chunk >> 7;       // c-block
            uint4 val = *(const uint4*)&SMEM[row * 128 + ((blk ^ (row & 7)) << 3)];
            const int tt = (n0 + row) & 2047;
            const int kt = tt >> 6, tk = tt & 63, sb = tk >> 5, qh = tk & 31;
            const int c = m0 + blk * 8;
            const int hh = (c >> 6) & 7, d = c & 63;
            const int kap = d >> 4, hb = (d >> 3) & 1;
            size_t off = (size_t)(bidx * 8 + hh) * 131072
                       + (size_t)(((((kt * 2 + sb) * 4 + kap) * 2 + hb) * 32 + qh) * 8);
            *(uint4*)&Y[off] = val;
        }
    } else {
        const int bidx = n0 >> 11;
        #pragma unroll
        for (int s = 0; s < 4; s++) {
            const int chunk = s * 512 + tid;
            const int rowc = chunk & 127;     // c
            const int blk = chunk >> 7;       // t-block
            uint4 val = *(const uint4*)&SMEM[rowc * 128 + ((blk ^ (rowc & 7)) << 3)];
            const int c = m0 + rowc;
            const int hh = (c >> 6) & 7, d = c & 63;
            const int qh = d & 31, db = (d >> 5) & 1;
            const int tt0 = (n0 + blk * 8) & 2047;
            const int kt = tt0 >> 6, kk = tt0 & 63;
            const int kc = kk >> 4, hb = (kk >> 3) & 1;
            size_t off = (size_t)(bidx * 8 + hh) * 131072
                       + (size_t)(((((kt * 2 + db) * 4 + kc) * 2 + hb) * 32 + qh) * 8);
            *(uint4*)&Y[off] = val;
        }
    }
}

// ---- combined output projection (NB=64): d_out = Wc[512][1024].AG[n][1024] + mixed bias ----
__global__ __launch_bounds__(256)
void gemm_comb_kernel(const ushort* __restrict__ Wp,
                      const float* __restrict__ bl, const float* __restrict__ bg,
                      const ushort* __restrict__ XTp, float* __restrict__ Y,
                      const int* __restrict__ tarr)
{
    GEMM_BODY(Wp, XTp, 1024, 64)

    const int bidx = (n0 + wn * 32) >> 11;
    float tn = (float)tarr[bidx] / 999.0f;
    float sl = sqrtf(tn), sg = sqrtf(1.0f - tn);

    #pragma unroll
    for (int mi = 0; mi < 4; mi++) {
        const int mb = m0 + wm * 64 + mi * 16 + 4 * gq;
        float bv[4];
        #pragma unroll
        for (int r = 0; r < 4; r++) bv[r] = sl * bl[mb + r] + sg * bg[mb + r];
        #pragma unroll
        for (int nj = 0; nj < 2; nj++) {
            const int tt = (n0 + wn * 32 + nj * 16 + x) & 2047;
            f32x4 v = acc[mi][nj];
            #pragma unroll
            for (int r = 0; r < 4; r++)
                Y[((size_t)bidx * 512 + mb + r) * 2048 + tt] = v[r] + bv[r];
        }
    }
}

// ======================= local windowed attention (bf16 [t][c] in, sl-scaled out) =======================
__global__ __launch_bounds__(256)
void local_attn_kernel(const ushort* __restrict__ qt, const ushort* __restrict__ kt,
                       const ushort* __restrict__ vt, ushort* __restrict__ outb,
                       const int* __restrict__ tarr)
{
    int gidx = blockIdx.x * 256 + threadIdx.x;
    int t  = gidx & (TT - 1);
    int bh = gidx >> 11;
    int h  = bh & (HH - 1);
    int b  = bh >> 3;
    const size_t rb = (size_t)b * TT;
    const int co = h * DD;
    const float wl = sqrtf((float)tarr[b] / 999.0f);

    float qf[64];
    {
        const ushort* qp = qt + (rb + t) * 512 + co;
        #pragma unroll
        for (int i = 0; i < 8; i++) {
            short8 v = *(const short8*)&qp[i * 8];
            #pragma unroll
            for (int j = 0; j < 8; j++) qf[i * 8 + j] = bf2f((ushort)v[j]);
        }
    }

    int koff[16]; float msk[16];
    #pragma unroll
    for (int w = 0; w < 16; w++) {
        int kidx = t + w - 8;
        msk[w]  = (kidx >= 0 && kidx < TT) ? 1.0f : 0.0f;
        koff[w] = min(max(kidx, 0), TT - 1);
    }

    float dots[16];
    #pragma unroll
    for (int w = 0; w < 16; w++) {
        const ushort* kp = kt + (rb + koff[w]) * 512 + co;
        float d0 = 0.f, d1 = 0.f;
        #pragma unroll
        for (int i = 0; i < 8; i++) {
            short8 v = *(const short8*)&kp[i * 8];
            #pragma unroll
            for (int j = 0; j < 8; j += 2) {
                d0 = fmaf(qf[i * 8 + j],     bf2f((ushort)v[j]),     d0);
                d1 = fmaf(qf[i * 8 + j + 1], bf2f((ushort)v[j + 1]), d1);
            }
        }
        dots[w] = d0 + d1;
    }

    float m = -1e30f;
    #pragma unroll
    for (int w = 0; w < 16; w++) { dots[w] = dots[w] * SCALE * msk[w]; m = fmaxf(m, dots[w]); }
    float p[16], s = 0.f;
    #pragma unroll
    for (int w = 0; w < 16; w++) { p[w] = __expf(dots[w] - m); s += p[w]; }
    float inv = wl / s;
    #pragma unroll
    for (int w = 0; w < 16; w++) p[w] *= msk[w] * inv;

    float oa[64];
    #pragma unroll
    for (int d = 0; d < 64; d++) oa[d] = 0.f;
    #pragma unroll
    for (int w = 0; w < 16; w++) {
        const ushort* vp = vt + (rb + koff[w]) * 512 + co;
        #pragma unroll
        for (int i = 0; i < 8; i++) {
            short8 v = *(const short8*)&vp[i * 8];
            #pragma unroll
            for (int j = 0; j < 8; j++)
                oa[i * 8 + j] = fmaf(p[w], bf2f((ushort)v[j]), oa[i * 8 + j]);
        }
    }

    ushort* op = outb + ((size_t)b * CC + co + (t >> 5)) * TT + (size_t)(t & 31) * DD;
    #pragma unroll
    for (int i = 0; i < 16; i++) {
        uint lo = (uint)f2bf(oa[i * 4 + 0]) | ((uint)f2bf(oa[i * 4 + 1]) << 16);
        uint hi = (uint)f2bf(oa[i * 4 + 2]) | ((uint)f2bf(oa[i * 4 + 3]) << 16);
        *(uint2*)&op[i * 4] = make_uint2(lo, hi);
    }
}

// ======================= global flash attention (in-block K-split x2, 8 waves, LDS combine) =======================
__global__ __launch_bounds__(512)
void flash_global_kernel(const ushort* __restrict__ qtd, const ushort* __restrict__ KT,
                         const ushort* __restrict__ VT, ushort* __restrict__ AG,
                         const int* __restrict__ tarr)
{
    __shared__ __align__(16) ushort Ks[2][2][4096];   // [grp][dbuf]
    __shared__ __align__(16) ushort Vs[2][2][4096];

    const int tid  = threadIdx.x;
    const int grp  = tid >> 8;          // K-half group (wave-uniform)
    const int t8   = tid & 255;
    const int w    = t8 >> 6;           // wave-in-group 0..3
    const int lane = tid & 63;
    const int qh   = lane & 31;
    const int h    = lane >> 5;

    const int bid = blockIdx.x;
    const int sw  = (bid & 7) * 64 + (bid >> 3);
    const int qt  = sw & 15;            // q-tile of 128
    const int p   = sw >> 4;            // b*8+hh
    const int hh  = p & 7, b = p >> 3;

    const size_t kvbase = (size_t)p * 131072 + (size_t)grp * (16 * 4096);
    const size_t btd    = (size_t)b * TT;
    const int q_glob = qt * 128 + w * 32 + qh;
    const float sg_mix = sqrtf(1.0f - (float)tarr[b] / 999.0f);

    short8 aQ[4];
    {
        const ushort* qrow = qtd + (btd + q_glob) * 512 + hh * 64;
        #pragma unroll
        for (int kap = 0; kap < 4; kap++)
            aQ[kap] = *(const short8*)&qrow[kap * 16 + h * 8];
    }

    f32x16 oacc[2];
    #pragma unroll
    for (int d = 0; d < 2; d++)
        #pragma unroll
        for (int r = 0; r < 16; r++) oacc[d][r] = 0.f;
    float l_run = 0.0f;

    const ushort* kA = KT + kvbase + (size_t)(2 * w) * 512 + lane * 8;
    const ushort* vA = VT + kvbase + (size_t)(2 * w) * 512 + lane * 8;

    auto issue = [&](int buf, int kt) {
        const size_t off = (size_t)kt * 4096;
        gload_lds16(kA + off,       &Ks[grp][buf][(2 * w) * 512]);
        gload_lds16(kA + off + 512, &Ks[grp][buf][(2 * w + 1) * 512]);
        gload_lds16(vA + off,       &Vs[grp][buf][(2 * w) * 512]);
        gload_lds16(vA + off + 512, &Vs[grp][buf][(2 * w + 1) * 512]);
    };
    issue(0, 0);

    int cur = 0;
    for (int kt = 0; kt < 16; kt++) {
        __syncthreads();
        if (kt < 15) issue(cur ^ 1, kt + 1);

        const ushort* KsC = &Ks[grp][cur][0];
        const ushort* VsC = &Vs[grp][cur][0];

        f32x16 ST[2];
        #pragma unroll
        for (int sb = 0; sb < 2; sb++)
            #pragma unroll
            for (int r = 0; r < 16; r++) ST[sb][r] = 0.f;
        __builtin_amdgcn_s_setprio(1);
        #pragma unroll
        for (int sb = 0; sb < 2; sb++)
            #pragma unroll
            for (int kap = 0; kap < 4; kap++) {
                short8 aK = *(const short8*)&KsC[(sb * 4 + kap) * 512 + lane * 8];
                ST[sb] = __builtin_amdgcn_mfma_f32_32x32x16_bf16(aK, aQ[kap], ST[sb], 0, 0, 0);
            }
        __builtin_amdgcn_s_setprio(0);

        float s0 = 0.f, s1 = 0.f, s2 = 0.f, s3 = 0.f;
        #pragma unroll
        for (int sb = 0; sb < 2; sb++)
            #pragma unroll
            for (int r = 0; r < 16; r += 4) {
                ST[sb][r + 0] = __builtin_amdgcn_exp2f(ST[sb][r + 0]);
                ST[sb][r + 1] = __builtin_amdgcn_exp2f(ST[sb][r + 1]);
                ST[sb][r + 2] = __builtin_amdgcn_exp2f(ST[sb][r + 2]);
                ST[sb][r + 3] = __builtin_amdgcn_exp2f(ST[sb][r + 3]);
                s0 += ST[sb][r + 0]; s1 += ST[sb][r + 1];
                s2 += ST[sb][r + 2]; s3 += ST[sb][r + 3];
            }
        l_run += (s0 + s1) + (s2 + s3);

        short8 bP[4];
        #pragma unroll
        for (int sb = 0; sb < 2; sb++)
            #pragma unroll
            for (int kcp = 0; kcp < 2; kcp++) {
                const int rb2 = kcp * 8;
                uint ca, cb, cc, cd;
                asm("v_cvt_pk_bf16_f32 %0, %1, %2" : "=v"(ca) : "v"(ST[sb][rb2 + 0]), "v"(ST[sb][rb2 + 1]));
                asm("v_cvt_pk_bf16_f32 %0, %1, %2" : "=v"(cb) : "v"(ST[sb][rb2 + 2]), "v"(ST[sb][rb2 + 3]));
                asm("v_cvt_pk_bf16_f32 %0, %1, %2" : "=v"(cc) : "v"(ST[sb][rb2 + 4]), "v"(ST[sb][rb2 + 5]));
                asm("v_cvt_pk_bf16_f32 %0, %1, %2" : "=v"(cd) : "v"(ST[sb][rb2 + 6]), "v"(ST[sb][rb2 + 7]));
                u32x2 r1 = __builtin_amdgcn_permlane32_swap(ca, cc, false, false);
                u32x2 r2 = __builtin_amdgcn_permlane32_swap(cb, cd, false, false);
                uint4 bu = make_uint4(r1[0], r2[0], r1[1], r2[1]);
                bP[sb * 2 + kcp] = __builtin_bit_cast(short8, bu);
            }

        __builtin_amdgcn_s_setprio(1);
        #pragma unroll
        for (int db = 0; db < 2; db++)
            #pragma unroll
            for (int kc = 0; kc < 4; kc++) {
                short8 aV = *(const short8*)&VsC[(db * 4 + kc) * 512 + lane * 8];
                oacc[db] = __builtin_amdgcn_mfma_f32_32x32x16_bf16(aV, bP[kc], oacc[db], 0, 0, 0);
            }
        __builtin_amdgcn_s_setprio(0);
        cur ^= 1;
    }

    // ---- in-LDS combine: group 1 -> LDS, group 0 adds & stores ----
    __syncthreads();                      // all compute done; Ks/Vs now dead
    f32x4* OP = (f32x4*)&Ks[0][0][0];     // [8][256] f32x4 = 32KB
    float* LP = (float*)&Vs[0][0][0];     // 256 floats
    if (grp == 1) {
        #pragma unroll
        for (int j = 0; j < 8; j++)
            OP[j * 256 + t8] = (f32x4){oacc[j >> 2][(j & 3) * 4 + 0], oacc[j >> 2][(j & 3) * 4 + 1],
                                       oacc[j >> 2][(j & 3) * 4 + 2], oacc[j >> 2][(j & 3) * 4 + 3]};
        LP[t8] = l_run;
    }
    __syncthreads();
    if (grp == 0) {
        #pragma unroll
        for (int j = 0; j < 8; j++) {
            f32x4 o = OP[j * 256 + t8];
            oacc[j >> 2][(j & 3) * 4 + 0] += o[0];
            oacc[j >> 2][(j & 3) * 4 + 1] += o[1];
            oacc[j >> 2][(j & 3) * 4 + 2] += o[2];
            oacc[j >> 2][(j & 3) * 4 + 3] += o[3];
        }
        l_run += LP[t8];
        float ltot = l_run + __shfl_xor(l_run, 32);
        float inv = sg_mix / ltot;
        ushort* agrow = AG + (btd + q_glob) * 1024 + 512 + hh * 64;
        #pragma unroll
        for (int db = 0; db < 2; db++)
            #pragma unroll
            for (int rq = 0; rq < 4; rq++) {
                const int d0 = db * 32 + rq * 8 + h * 4;
                uint lo = (uint)f2bf(oacc[db][rq * 4 + 0] * inv) | ((uint)f2bf(oacc[db][rq * 4 + 1] * inv) << 16);
                uint hi = (uint)f2bf(oacc[db][rq * 4 + 2] * inv) | ((uint)f2bf(oacc[db][rq * 4 + 3] * inv) << 16);
                *(uint2*)&agrow[d0] = make_uint2(lo, hi);
            }
    }
}

// ======================= launch =======================
extern "C" void kernel_launch(void* const* d_in, const int* in_sizes, int n_in,
                              void* d_out, int out_size, void* d_ws, size_t ws_size,
                              hipStream_t stream)
{
    const float* x    = (const float*)d_in[0];
    const float* cond = (const float*)d_in[1];
    const int*   tarr = (const int*)d_in[2];
    const float* lq_w = (const float*)d_in[3];
    const float* lq_b = (const float*)d_in[4];
    const float* lk_w = (const float*)d_in[5];
    const float* lk_b = (const float*)d_in[6];
    const float* lv_w = (const float*)d_in[7];
    const float* lv_b = (const float*)d_in[8];
    const float* lo_w = (const float*)d_in[9];
    const float* lo_b = (const float*)d_in[10];
    const float* gq_w = (const float*)d_in[11];
    const float* gq_b = (const float*)d_in[12];
    const float* gk_w = (const float*)d_in[13];
    const float* gk_b = (const float*)d_in[14];
    const float* gv_w = (const float*)d_in[15];
    const float* gv_b = (const float*)d_in[16];
    const float* go_w = (const float*)d_in[17];
    const float* go_b = (const float*)d_in[18];
    float* out = (float*)d_out;

    const size_t N = (size_t)BB * CC * TT;
    char* w = (char*)d_ws;
    ushort* xtb = (ushort*)w; w += N * 2;
    ushort* ctb = (ushort*)w; w += N * 2;
    ushort* lq  = (ushort*)w; w += N * 2;
    ushort* lk  = (ushort*)w; w += N * 2;
    ushort* lv  = (ushort*)w; w += N * 2;
    ushort* gqb = (ushort*)w; w += N * 2;
    ushort* ktb = (ushort*)w; w += N * 2;     // fragment-tiled K
    ushort* vtb = (ushort*)w; w += N * 2;     // fragment-tiled V
    ushort* scr = (ushort*)w; w += N * 2;
    ushort* AG  = (ushort*)w; w += (size_t)BB * TT * 1024 * 2;
    ushort* wbf = (ushort*)w; w += (size_t)6 * 512 * 512 * 2;
    ushort* wc  = (ushort*)w; w += (size_t)512 * 1024 * 2;
    float* ctab = (float*)w;  w += (size_t)32 * 2048 * 4;
    float* stab = (float*)w;

    dim3 blk(256);

    prep_kernel<<<dim3(4352), blk, 0, stream>>>(x, cond,
                                                lq_w, lk_w, lv_w, gq_w, gk_w, gv_w, lo_w, go_w,
                                                wbf, wc, xtb, ctb, ctab, stab);

    gemm6_kernel<<<dim3(64, 4, 6), dim3(512), 0, stream>>>(wbf, lq_b, lk_b, lv_b, gq_b, gk_b, gv_b,
                                                           xtb, ctb, lq, lk, lv, gqb, ktb, vtb, ctab, stab);

    local_attn_kernel<<<dim3(BB * HH * TT / 256), blk, 0, stream>>>(lq, lk, lv, scr, tarr);
    transpose_bf16_kernel<<<dim3(32, 8, BB), blk, 0, stream>>>(scr, AG);

    flash_global_kernel<<<dim3(512), dim3(512), 0, stream>>>(gqb, ktb, vtb, AG, tarr);

    gemm_comb_kernel<<<dim3(128, 4), blk, 0, stream>>>(wc, lo_b, go_b, AG, out, tarr);
}

// Round 18
// 165.372 us; speedup vs baseline: 1.5010x; 1.5010x over previous
//
#include <hip/hip_runtime.h>
#include <math.h>

#define BB 4
#define CC 512
#define TT 2048
#define HH 8
#define DD 64

static constexpr float SCALE = 0.125f;                 // D^-0.5
static constexpr float QK_SCALE_LOG2 = 0.125f * 1.4426950408889634f;  // fold log2(e): softmax in exp2 domain

typedef __attribute__((ext_vector_type(8)))  short  short8;
typedef __attribute__((ext_vector_type(4)))  float  f32x4;
typedef __attribute__((ext_vector_type(16))) float  f32x16;
typedef __attribute__((ext_vector_type(2)))  unsigned int u32x2;

static __device__ __forceinline__ ushort f2bf(float f) {
    uint u = __float_as_uint(f);
    uint r = (u + 0x7fffu + ((u >> 16) & 1u)) >> 16;
    return (ushort)r;
}
static __device__ __forceinline__ float bf2f(ushort u) {
    return __uint_as_float((uint)u << 16);
}

typedef unsigned int u32;
typedef u32 __attribute__((address_space(1))) gu32;
typedef u32 __attribute__((address_space(3))) lu32;
static __device__ __forceinline__ void gload_lds16(const void* g, void* l) {
    __builtin_amdgcn_global_load_lds((const gu32*)g, (lu32*)l, 16, 0, 0);
}

// ======================= fused prep: rope table + weight cvt + input transpose =======================
__global__ __launch_bounds__(256)
void prep_kernel(const float* __restrict__ x, const float* __restrict__ cond,
                 const float* w0, const float* w1, const float* w2, const float* w3,
                 const float* w4, const float* w5, const float* w6, const float* w7,
                 ushort* __restrict__ wbf, ushort* __restrict__ wc,
                 ushort* __restrict__ xtb, ushort* __restrict__ ctb,
                 float* __restrict__ ctab, float* __restrict__ stab)
{
    __shared__ ushort L[64][66];
    int bid = blockIdx.x;
    const int tid = threadIdx.x;

    if (bid < 256) {                       // ---- rope table ----
        int idx = bid * 256 + tid;         // 64K threads: [i][t]
        int i = idx >> 11;
        int t = idx & 2047;
        float ex   = (2.0f * (float)i) / 64.0f;
        float invf = powf(10000.0f, -ex);
        float ang  = (float)t * invf;
        ctab[idx] = cosf(ang);
        stab[idx] = sinf(ang);
        return;
    }
    bid -= 256;
    if (bid < 2048) {                      // ---- weight fp32 -> bf16 ----
        const float* srcs[8] = {w0, w1, w2, w3, w4, w5, w6, w7};
        int wi = bid >> 8;
        int idx = ((bid & 255) * 256 + tid) * 4;
        float4 v = *(const float4*)&srcs[wi][idx];
        uint lo = (uint)f2bf(v.x) | ((uint)f2bf(v.y) << 16);
        uint hi = (uint)f2bf(v.z) | ((uint)f2bf(v.w) << 16);
        uint2 pk = make_uint2(lo, hi);
        if (wi < 6) {
            *(uint2*)&wbf[(size_t)wi * 262144 + idx] = pk;
        } else {
            int row = idx >> 9, col = idx & 511;
            *(uint2*)&wc[(size_t)row * 1024 + (wi - 6) * 512 + col] = pk;
        }
        return;
    }
    bid -= 2048;                           // ---- transpose [b][c][t] -> bf16 [b][t][c] ----
    const int z = bid >> 8;                // 0..7
    const int r = bid & 255;
    const float* in = (z < 4) ? x : cond;
    ushort* outp    = (z < 4) ? xtb : ctb;
    const int b = z & 3;
    const int t0 = (r & 31) * 64, c0 = (r >> 5) * 64;
    const float* inb = in + (size_t)b * CC * TT;
    ushort* outb = outp + (size_t)b * TT * CC;
    const int lc = tid >> 6;
    const int lt = tid & 63;
    #pragma unroll
    for (int i = 0; i < 16; i++) {
        int c = i * 4 + lc;
        L[c][lt] = f2bf(inb[(size_t)(c0 + c) * TT + t0 + lt]);
    }
    __syncthreads();
    #pragma unroll
    for (int i = 0; i < 16; i++) {
        int t = i * 4 + lc;
        outb[(size_t)(t0 + t) * CC + c0 + lt] = L[lt][t];
    }
}

// ---- scrambled local-attn output [b][c][t] -> AG[b][t][0..512) (row stride 1024) ----
__global__ __launch_bounds__(256)
void transpose_bf16_kernel(const ushort* __restrict__ in, ushort* __restrict__ AG)
{
    __shared__ ushort L[64][66];
    const int t0 = blockIdx.x * 64, c0 = blockIdx.y * 64, b = blockIdx.z;
    const ushort* inb = in + (size_t)b * CC * TT;
    ushort* outb = AG + (size_t)b * TT * 1024;
    const int lc = threadIdx.x >> 6;
    const int lt = threadIdx.x & 63;
    #pragma unroll
    for (int i = 0; i < 16; i++) {
        int c = i * 4 + lc;
        L[c][lt] = inb[(size_t)(c0 + c) * TT + t0 + lt];
    }
    __syncthreads();
    #pragma unroll
    for (int i = 0; i < 16; i++) {
        int t = i * 4 + lc;
        outb[(size_t)(t0 + t) * 1024 + c0 + lt] = L[lt][t];
    }
}

// ======================= MFMA GEMM core (macro used by gemm_comb only) =======================
#define GEMM_BODY(Wp, XTp, KD, NB)                                                  \
    __shared__ __align__(16) ushort As[2][128][32];                                 \
    __shared__ __align__(16) ushort Bs[2][NB][32];                                  \
    const int tid  = threadIdx.x;                                                   \
    const int wid  = tid >> 6;                                                      \
    const int lane = tid & 63;                                                      \
    const int x  = lane & 15;                                                       \
    const int gq = lane >> 4;                                                       \
    const int wm = wid >> 1, wn = wid & 1;                                          \
    const int m0 = blockIdx.y * 128;                                                \
    const int n0 = blockIdx.x * NB;                                                 \
    const int srow = lane >> 2;                                                     \
    const int sblk = lane & 3;                                                      \
    f32x4 acc[4][NB / 32];                                                          \
    _Pragma("unroll")                                                               \
    for (int i = 0; i < 4; i++)                                                     \
        _Pragma("unroll")                                                           \
        for (int j = 0; j < NB / 32; j++) acc[i][j] = (f32x4){0.f, 0.f, 0.f, 0.f};  \
    auto stage = [&](int bf, int k0) {                                              \
        _Pragma("unroll")                                                           \
        for (int c = 0; c < 2; c++) {                                               \
            int row = c * 64 + wid * 16 + srow;                                     \
            int dbk = sblk ^ ((row >> 1) & 3);                                      \
            gload_lds16(&Wp[(size_t)(m0 + row) * KD + k0 + dbk * 8],                \
                        &As[bf][c * 64 + wid * 16][0]);                             \
            if (c * 64 < NB)                                                        \
                gload_lds16(&XTp[(size_t)(n0 + row) * KD + k0 + dbk * 8],           \
                            &Bs[bf][c * 64 + wid * 16][0]);                         \
        }                                                                           \
    };                                                                              \
    stage(0, 0);                                                                    \
    __syncthreads();                                                                \
    for (int ks = 0; ks < (KD) / 32; ks++) {                                        \
        int cur = ks & 1;                                                           \
        if (ks < (KD) / 32 - 1) stage(cur ^ 1, (ks + 1) * 32);                      \
        short8 aF[4], bF[NB / 32];                                                  \
        _Pragma("unroll")                                                           \
        for (int mi = 0; mi < 4; mi++) {                                            \
            int row = wm * 64 + mi * 16 + x;                                        \
            aF[mi] = *(const short8*)&As[cur][row][(gq ^ ((row >> 1) & 3)) * 8];    \
        }                                                                           \
        _Pragma("unroll")                                                           \
        for (int nj = 0; nj < NB / 32; nj++) {                                      \
            int row = wn * (NB / 2) + nj * 16 + x;                                  \
            bF[nj] = *(const short8*)&Bs[cur][row][(gq ^ ((row >> 1) & 3)) * 8];    \
        }                                                                           \
        _Pragma("unroll")                                                           \
        for (int mi = 0; mi < 4; mi++)                                              \
            _Pragma("unroll")                                                       \
            for (int nj = 0; nj < NB / 32; nj++)                                    \
                acc[mi][nj] = __builtin_amdgcn_mfma_f32_16x16x32_bf16(aF[mi], bF[nj], acc[mi][nj], 0, 0, 0); \
        __syncthreads();                                                            \
    }

// ---- all 6 qkv projections, 8-WAVE blocks (wave grid 2m x 4n; 64x32 per wave) ----
// launch_bounds(512,4): 128-VGPR budget (body needs ~70) -> 2 blocks/CU, NO spills.
// (r17's (512,6) forced 40 VGPR -> scratch spill catastrophe: WRITE_SIZE 380MB.)
__global__ __launch_bounds__(512, 4)
void gemm6_kernel(const ushort* __restrict__ wbase,
                  const float* __restrict__ b0, const float* __restrict__ b1, const float* __restrict__ b2,
                  const float* __restrict__ b3, const float* __restrict__ b4, const float* __restrict__ b5,
                  const ushort* __restrict__ xtb, const ushort* __restrict__ ctb,
                  ushort* __restrict__ y0, ushort* __restrict__ y1, ushort* __restrict__ y2,
                  ushort* __restrict__ y3, ushort* __restrict__ y4, ushort* __restrict__ y5,
                  const float* __restrict__ ctab, const float* __restrict__ stab)
{
    __shared__ __align__(16) ushort SMEM[16384];   // As[2][128][32] | Bs[2][128][32] | bounce(128x128)
    ushort (*As)[128][32] = (ushort(*)[128][32])&SMEM[0];
    ushort (*Bs)[128][32] = (ushort(*)[128][32])&SMEM[8192];

    const int z = blockIdx.z;
    const ushort* Wp  = wbase + (size_t)z * 262144;
    const float* bias = (z == 0) ? b0 : (z == 1) ? b1 : (z == 2) ? b2 : (z == 3) ? b3 : (z == 4) ? b4 : b5;
    const ushort* XTp = (z == 0 || z == 3) ? xtb : ctb;
    ushort* Y = (z == 0) ? y0 : (z == 1) ? y1 : (z == 2) ? y2 : (z == 3) ? y3 : (z == 4) ? y4 : y5;
    const bool do_rope = (z == 3 || z == 4);
    const bool swp = (z == 5);
    const float qscale = (z == 3) ? QK_SCALE_LOG2 : 1.0f;

    const int tid  = threadIdx.x;          // 0..511
    const int wid  = tid >> 6;             // 0..7
    const int lane = tid & 63;
    const int x  = lane & 15;
    const int gq = lane >> 4;
    const int wm = wid >> 2;               // 0..1 (64 m-rows each)
    const int wn = wid & 3;                // 0..3 (32 n-rows each)
    const int m0 = blockIdx.y * 128;
    const int n0 = blockIdx.x * 128;
    const int srow = lane >> 2;
    const int sblk = lane & 3;

    f32x4 acc[4][2];
    #pragma unroll
    for (int i = 0; i < 4; i++)
        #pragma unroll
        for (int j = 0; j < 2; j++) acc[i][j] = (f32x4){0.f, 0.f, 0.f, 0.f};

    // 512 threads cover 128 rows x 4 chunks per matrix: 1 gload A + 1 gload B each.
    auto stage = [&](int bf, int k0) {
        int row = wid * 16 + srow;                     // 0..127
        int dbk = sblk ^ ((row >> 1) & 3);
        gload_lds16(&Wp[(size_t)(m0 + row) * 512 + k0 + dbk * 8],
                    &As[bf][wid * 16][0]);
        gload_lds16(&XTp[(size_t)(n0 + row) * 512 + k0 + dbk * 8],
                    &Bs[bf][wid * 16][0]);
    };
    stage(0, 0);
    __syncthreads();

    for (int ks = 0; ks < 16; ks++) {
        int cur = ks & 1;
        if (ks < 15) stage(cur ^ 1, (ks + 1) * 32);
        short8 aF[4], bF[2];
        #pragma unroll
        for (int mi = 0; mi < 4; mi++) {
            int row = wm * 64 + mi * 16 + x;
            aF[mi] = *(const short8*)&As[cur][row][(gq ^ ((row >> 1) & 3)) * 8];
        }
        #pragma unroll
        for (int nj = 0; nj < 2; nj++) {
            int row = wn * 32 + nj * 16 + x;
            bF[nj] = *(const short8*)&Bs[cur][row][(gq ^ ((row >> 1) & 3)) * 8];
        }
        if (swp) {          // z5: D[n][m] — thread holds 4 consecutive t for fixed c
            #pragma unroll
            for (int mi = 0; mi < 4; mi++)
                #pragma unroll
                for (int nj = 0; nj < 2; nj++)
                    acc[mi][nj] = __builtin_amdgcn_mfma_f32_16x16x32_bf16(bF[nj], aF[mi], acc[mi][nj], 0, 0, 0);
        } else {            // D[m][n]
            #pragma unroll
            for (int mi = 0; mi < 4; mi++)
                #pragma unroll
                for (int nj = 0; nj < 2; nj++)
                    acc[mi][nj] = __builtin_amdgcn_mfma_f32_16x16x32_bf16(aF[mi], bF[nj], acc[mi][nj], 0, 0, 0);
        }
        __syncthreads();
    }

    // ---- bounce write: bias (+rope), pack 4 bf16 -> 8B into swizzled 128x128 tile ----
    if (!swp) {
        #pragma unroll
        for (int mi = 0; mi < 4; mi++) {
            const int cL = wm * 64 + mi * 16 + 4 * gq;
            const int mb = m0 + cL;
            float bv[4];
            #pragma unroll
            for (int r = 0; r < 4; r++) bv[r] = bias[mb + r];
            #pragma unroll
            for (int nj = 0; nj < 2; nj++) {
                const int tL = wn * 32 + nj * 16 + x;
                const int tt = (n0 + tL) & 2047;
                f32x4 v = acc[mi][nj];
                v[0] += bv[0]; v[1] += bv[1]; v[2] += bv[2]; v[3] += bv[3];
                if (do_rope) {
                    const int i0 = (mb & 63) >> 1;
                    float c0 = ctab[(size_t)i0 * 2048 + tt],       s0 = stab[(size_t)i0 * 2048 + tt];
                    float c1 = ctab[(size_t)(i0 + 1) * 2048 + tt], s1 = stab[(size_t)(i0 + 1) * 2048 + tt];
                    float e0 = (v[0] * c0 - v[1] * s0) * qscale;
                    float e1 = (v[0] * s0 + v[1] * c0) * qscale;
                    float e2 = (v[2] * c1 - v[3] * s1) * qscale;
                    float e3 = (v[2] * s1 + v[3] * c1) * qscale;
                    v[0] = e0; v[1] = e1; v[2] = e2; v[3] = e3;
                }
                uint lo = (uint)f2bf(v[0]) | ((uint)f2bf(v[1]) << 16);
                uint hi = (uint)f2bf(v[2]) | ((uint)f2bf(v[3]) << 16);
                const int blk = (cL >> 3) ^ (tL & 7);
                *(uint2*)&SMEM[tL * 128 + blk * 8 + (gq & 1) * 4] = make_uint2(lo, hi);
            }
        }
    } else {
        #pragma unroll
        for (int mi = 0; mi < 4; mi++) {
            const int cL = wm * 64 + mi * 16 + x;
            const float bv = bias[m0 + cL];
            #pragma unroll
            for (int nj = 0; nj < 2; nj++) {
                const int tL = wn * 32 + nj * 16 + 4 * gq;
                f32x4 v = acc[mi][nj];
                uint lo = (uint)f2bf(v[0] + bv) | ((uint)f2bf(v[1] + bv) << 16);
                uint hi = (uint)f2bf(v[2] + bv) | ((uint)f2bf(v[3] + bv) << 16);
                const int blk = (tL >> 3) ^ (cL & 7);
                *(uint2*)&SMEM[cL * 128 + blk * 8 + (gq & 1) * 4] = make_uint2(lo, hi);
            }
        }
    }
    __syncthreads();

    // ---- coalesced global stores (16B/thread, 4 sweeps of 512 threads) ----
    if (z <= 3) {
        #pragma unroll
        for (int s = 0; s < 4; s++) {
            const int chunk = s * 512 + tid;
            const int row = chunk >> 4;       // t
            const int blk = chunk & 15;       // c-block
            uint4 val = *(const uint4*)&SMEM[row * 128 + ((blk ^ (row & 7)) << 3)];
            *(uint4*)&Y[(size_t)(n0 + row) * 512 + m0 + blk * 8] = val;
        }
    } else if (z == 4) {
        const int bidx = n0 >> 11;
        #pragma unroll
        for (int s = 0; s < 4; s++) {
            const int chunk = s * 512 + tid;
            const int row = chunk & 127;      // t
            const int blk = chunk >> 7;       // c-block
            uint4 val = *(const uint4*)&SMEM[row * 128 + ((blk ^ (row & 7)) << 3)];
            const int tt = (n0 + row) & 2047;
            const int kt = tt >> 6, tk = tt & 63, sb = tk >> 5, qh = tk & 31;
            const int c = m0 + blk * 8;
            const int hh = (c >> 6) & 7, d = c & 63;
            const int kap = d >> 4, hb = (d >> 3) & 1;
            size_t off = (size_t)(bidx * 8 + hh) * 131072
                       + (size_t)(((((kt * 2 + sb) * 4 + kap) * 2 + hb) * 32 + qh) * 8);
            *(uint4*)&Y[off] = val;
        }
    } else {
        const int bidx = n0 >> 11;
        #pragma unroll
        for (int s = 0; s < 4; s++) {
            const int chunk = s * 512 + tid;
            const int rowc = chunk & 127;     // c
            const int blk = chunk >> 7;       // t-block
            uint4 val = *(const uint4*)&SMEM[rowc * 128 + ((blk ^ (rowc & 7)) << 3)];
            const int c = m0 + rowc;
            const int hh = (c >> 6) & 7, d = c & 63;
            const int qh = d & 31, db = (d >> 5) & 1;
            const int tt0 = (n0 + blk * 8) & 2047;
            const int kt = tt0 >> 6, kk = tt0 & 63;
            const int kc = kk >> 4, hb = (kk >> 3) & 1;
            size_t off = (size_t)(bidx * 8 + hh) * 131072
                       + (size_t)(((((kt * 2 + db) * 4 + kc) * 2 + hb) * 32 + qh) * 8);
            *(uint4*)&Y[off] = val;
        }
    }
}

// ---- combined output projection (NB=64): d_out = Wc[512][1024].AG[n][1024] + mixed bias ----
__global__ __launch_bounds__(256)
void gemm_comb_kernel(const ushort* __restrict__ Wp,
                      const float* __restrict__ bl, const float* __restrict__ bg,
                      const ushort* __restrict__ XTp, float* __restrict__ Y,
                      const int* __restrict__ tarr)
{
    GEMM_BODY(Wp, XTp, 1024, 64)

    const int bidx = (n0 + wn * 32) >> 11;
    float tn = (float)tarr[bidx] / 999.0f;
    float sl = sqrtf(tn), sg = sqrtf(1.0f - tn);

    #pragma unroll
    for (int mi = 0; mi < 4; mi++) {
        const int mb = m0 + wm * 64 + mi * 16 + 4 * gq;
        float bv[4];
        #pragma unroll
        for (int r = 0; r < 4; r++) bv[r] = sl * bl[mb + r] + sg * bg[mb + r];
        #pragma unroll
        for (int nj = 0; nj < 2; nj++) {
            const int tt = (n0 + wn * 32 + nj * 16 + x) & 2047;
            f32x4 v = acc[mi][nj];
            #pragma unroll
            for (int r = 0; r < 4; r++)
                Y[((size_t)bidx * 512 + mb + r) * 2048 + tt] = v[r] + bv[r];
        }
    }
}

// ======================= local windowed attention (bf16 [t][c] in, sl-scaled out) =======================
__global__ __launch_bounds__(256)
void local_attn_kernel(const ushort* __restrict__ qt, const ushort* __restrict__ kt,
                       const ushort* __restrict__ vt, ushort* __restrict__ outb,
                       const int* __restrict__ tarr)
{
    int gidx = blockIdx.x * 256 + threadIdx.x;
    int t  = gidx & (TT - 1);
    int bh = gidx >> 11;
    int h  = bh & (HH - 1);
    int b  = bh >> 3;
    const size_t rb = (size_t)b * TT;
    const int co = h * DD;
    const float wl = sqrtf((float)tarr[b] / 999.0f);

    float qf[64];
    {
        const ushort* qp = qt + (rb + t) * 512 + co;
        #pragma unroll
        for (int i = 0; i < 8; i++) {
            short8 v = *(const short8*)&qp[i * 8];
            #pragma unroll
            for (int j = 0; j < 8; j++) qf[i * 8 + j] = bf2f((ushort)v[j]);
        }
    }

    int koff[16]; float msk[16];
    #pragma unroll
    for (int w = 0; w < 16; w++) {
        int kidx = t + w - 8;
        msk[w]  = (kidx >= 0 && kidx < TT) ? 1.0f : 0.0f;
        koff[w] = min(max(kidx, 0), TT - 1);
    }

    float dots[16];
    #pragma unroll
    for (int w = 0; w < 16; w++) {
        const ushort* kp = kt + (rb + koff[w]) * 512 + co;
        float d0 = 0.f, d1 = 0.f;
        #pragma unroll
        for (int i = 0; i < 8; i++) {
            short8 v = *(const short8*)&kp[i * 8];
            #pragma unroll
            for (int j = 0; j < 8; j += 2) {
                d0 = fmaf(qf[i * 8 + j],     bf2f((ushort)v[j]),     d0);
                d1 = fmaf(qf[i * 8 + j + 1], bf2f((ushort)v[j + 1]), d1);
            }
        }
        dots[w] = d0 + d1;
    }

    float m = -1e30f;
    #pragma unroll
    for (int w = 0; w < 16; w++) { dots[w] = dots[w] * SCALE * msk[w]; m = fmaxf(m, dots[w]); }
    float p[16], s = 0.f;
    #pragma unroll
    for (int w = 0; w < 16; w++) { p[w] = __expf(dots[w] - m); s += p[w]; }
    float inv = wl / s;
    #pragma unroll
    for (int w = 0; w < 16; w++) p[w] *= msk[w] * inv;

    float oa[64];
    #pragma unroll
    for (int d = 0; d < 64; d++) oa[d] = 0.f;
    #pragma unroll
    for (int w = 0; w < 16; w++) {
        const ushort* vp = vt + (rb + koff[w]) * 512 + co;
        #pragma unroll
        for (int i = 0; i < 8; i++) {
            short8 v = *(const short8*)&vp[i * 8];
            #pragma unroll
            for (int j = 0; j < 8; j++)
                oa[i * 8 + j] = fmaf(p[w], bf2f((ushort)v[j]), oa[i * 8 + j]);
        }
    }

    ushort* op = outb + ((size_t)b * CC + co + (t >> 5)) * TT + (size_t)(t & 31) * DD;
    #pragma unroll
    for (int i = 0; i < 16; i++) {
        uint lo = (uint)f2bf(oa[i * 4 + 0]) | ((uint)f2bf(oa[i * 4 + 1]) << 16);
        uint hi = (uint)f2bf(oa[i * 4 + 2]) | ((uint)f2bf(oa[i * 4 + 3]) << 16);
        *(uint2*)&op[i * 4] = make_uint2(lo, hi);
    }
}

// ======================= global flash attention (in-block K-split x2, 8 waves, LDS combine) =======================
__global__ __launch_bounds__(512)
void flash_global_kernel(const ushort* __restrict__ qtd, const ushort* __restrict__ KT,
                         const ushort* __restrict__ VT, ushort* __restrict__ AG,
                         const int* __restrict__ tarr)
{
    __shared__ __align__(16) ushort Ks[2][2][4096];   // [grp][dbuf]
    __shared__ __align__(16) ushort Vs[2][2][4096];

    const int tid  = threadIdx.x;
    const int grp  = tid >> 8;          // K-half group (wave-uniform)
    const int t8   = tid & 255;
    const int w    = t8 >> 6;           // wave-in-group 0..3
    const int lane = tid & 63;
    const int qh   = lane & 31;
    const int h    = lane >> 5;

    const int bid = blockIdx.x;
    const int sw  = (bid & 7) * 64 + (bid >> 3);
    const int qt  = sw & 15;            // q-tile of 128
    const int p   = sw >> 4;            // b*8+hh
    const int hh  = p & 7, b = p >> 3;

    const size_t kvbase = (size_t)p * 131072 + (size_t)grp * (16 * 4096);
    const size_t btd    = (size_t)b * TT;
    const int q_glob = qt * 128 + w * 32 + qh;
    const float sg_mix = sqrtf(1.0f - (float)tarr[b] / 999.0f);

    short8 aQ[4];
    {
        const ushort* qrow = qtd + (btd + q_glob) * 512 + hh * 64;
        #pragma unroll
        for (int kap = 0; kap < 4; kap++)
            aQ[kap] = *(const short8*)&qrow[kap * 16 + h * 8];
    }

    f32x16 oacc[2];
    #pragma unroll
    for (int d = 0; d < 2; d++)
        #pragma unroll
        for (int r = 0; r < 16; r++) oacc[d][r] = 0.f;
    float l_run = 0.0f;

    const ushort* kA = KT + kvbase + (size_t)(2 * w) * 512 + lane * 8;
    const ushort* vA = VT + kvbase + (size_t)(2 * w) * 512 + lane * 8;

    auto issue = [&](int buf, int kt) {
        const size_t off = (size_t)kt * 4096;
        gload_lds16(kA + off,       &Ks[grp][buf][(2 * w) * 512]);
        gload_lds16(kA + off + 512, &Ks[grp][buf][(2 * w + 1) * 512]);
        gload_lds16(vA + off,       &Vs[grp][buf][(2 * w) * 512]);
        gload_lds16(vA + off + 512, &Vs[grp][buf][(2 * w + 1) * 512]);
    };
    issue(0, 0);

    int cur = 0;
    for (int kt = 0; kt < 16; kt++) {
        __syncthreads();
        if (kt < 15) issue(cur ^ 1, kt + 1);

        const ushort* KsC = &Ks[grp][cur][0];
        const ushort* VsC = &Vs[grp][cur][0];

        f32x16 ST[2];
        #pragma unroll
        for (int sb = 0; sb < 2; sb++)
            #pragma unroll
            for (int r = 0; r < 16; r++) ST[sb][r] = 0.f;
        __builtin_amdgcn_s_setprio(1);
        #pragma unroll
        for (int sb = 0; sb < 2; sb++)
            #pragma unroll
            for (int kap = 0; kap < 4; kap++) {
                short8 aK = *(const short8*)&KsC[(sb * 4 + kap) * 512 + lane * 8];
                ST[sb] = __builtin_amdgcn_mfma_f32_32x32x16_bf16(aK, aQ[kap], ST[sb], 0, 0, 0);
            }
        __builtin_amdgcn_s_setprio(0);

        float s0 = 0.f, s1 = 0.f, s2 = 0.f, s3 = 0.f;
        #pragma unroll
        for (int sb = 0; sb < 2; sb++)
            #pragma unroll
            for (int r = 0; r < 16; r += 4) {
                ST[sb][r + 0] = __builtin_amdgcn_exp2f(ST[sb][r + 0]);
                ST[sb][r + 1] = __builtin_amdgcn_exp2f(ST[sb][r + 1]);
                ST[sb][r + 2] = __builtin_amdgcn_exp2f(ST[sb][r + 2]);
                ST[sb][r + 3] = __builtin_amdgcn_exp2f(ST[sb][r + 3]);
                s0 += ST[sb][r + 0]; s1 += ST[sb][r + 1];
                s2 += ST[sb][r + 2]; s3 += ST[sb][r + 3];
            }
        l_run += (s0 + s1) + (s2 + s3);

        short8 bP[4];
        #pragma unroll
        for (int sb = 0; sb < 2; sb++)
            #pragma unroll
            for (int kcp = 0; kcp < 2; kcp++) {
                const int rb2 = kcp * 8;
                uint ca, cb, cc, cd;
                asm("v_cvt_pk_bf16_f32 %0, %1, %2" : "=v"(ca) : "v"(ST[sb][rb2 + 0]), "v"(ST[sb][rb2 + 1]));
                asm("v_cvt_pk_bf16_f32 %0, %1, %2" : "=v"(cb) : "v"(ST[sb][rb2 + 2]), "v"(ST[sb][rb2 + 3]));
                asm("v_cvt_pk_bf16_f32 %0, %1, %2" : "=v"(cc) : "v"(ST[sb][rb2 + 4]), "v"(ST[sb][rb2 + 5]));
                asm("v_cvt_pk_bf16_f32 %0, %1, %2" : "=v"(cd) : "v"(ST[sb][rb2 + 6]), "v"(ST[sb][rb2 + 7]));
                u32x2 r1 = __builtin_amdgcn_permlane32_swap(ca, cc, false, false);
                u32x2 r2 = __builtin_amdgcn_permlane32_swap(cb, cd, false, false);
                uint4 bu = make_uint4(r1[0], r2[0], r1[1], r2[1]);
                bP[sb * 2 + kcp] = __builtin_bit_cast(short8, bu);
            }

        __builtin_amdgcn_s_setprio(1);
        #pragma unroll
        for (int db = 0; db < 2; db++)
            #pragma unroll
            for (int kc = 0; kc < 4; kc++) {
                short8 aV = *(const short8*)&VsC[(db * 4 + kc) * 512 + lane * 8];
                oacc[db] = __builtin_amdgcn_mfma_f32_32x32x16_bf16(aV, bP[kc], oacc[db], 0, 0, 0);
            }
        __builtin_amdgcn_s_setprio(0);
        cur ^= 1;
    }

    // ---- in-LDS combine: group 1 -> LDS, group 0 adds & stores ----
    __syncthreads();                      // all compute done; Ks/Vs now dead
    f32x4* OP = (f32x4*)&Ks[0][0][0];     // [8][256] f32x4 = 32KB
    float* LP = (float*)&Vs[0][0][0];     // 256 floats
    if (grp == 1) {
        #pragma unroll
        for (int j = 0; j < 8; j++)
            OP[j * 256 + t8] = (f32x4){oacc[j >> 2][(j & 3) * 4 + 0], oacc[j >> 2][(j & 3) * 4 + 1],
                                       oacc[j >> 2][(j & 3) * 4 + 2], oacc[j >> 2][(j & 3) * 4 + 3]};
        LP[t8] = l_run;
    }
    __syncthreads();
    if (grp == 0) {
        #pragma unroll
        for (int j = 0; j < 8; j++) {
            f32x4 o = OP[j * 256 + t8];
            oacc[j >> 2][(j & 3) * 4 + 0] += o[0];
            oacc[j >> 2][(j & 3) * 4 + 1] += o[1];
            oacc[j >> 2][(j & 3) * 4 + 2] += o[2];
            oacc[j >> 2][(j & 3) * 4 + 3] += o[3];
        }
        l_run += LP[t8];
        float ltot = l_run + __shfl_xor(l_run, 32);
        float inv = sg_mix / ltot;
        ushort* agrow = AG + (btd + q_glob) * 1024 + 512 + hh * 64;
        #pragma unroll
        for (int db = 0; db < 2; db++)
            #pragma unroll
            for (int rq = 0; rq < 4; rq++) {
                const int d0 = db * 32 + rq * 8 + h * 4;
                uint lo = (uint)f2bf(oacc[db][rq * 4 + 0] * inv) | ((uint)f2bf(oacc[db][rq * 4 + 1] * inv) << 16);
                uint hi = (uint)f2bf(oacc[db][rq * 4 + 2] * inv) | ((uint)f2bf(oacc[db][rq * 4 + 3] * inv) << 16);
                *(uint2*)&agrow[d0] = make_uint2(lo, hi);
            }
    }
}

// ======================= launch =======================
extern "C" void kernel_launch(void* const* d_in, const int* in_sizes, int n_in,
                              void* d_out, int out_size, void* d_ws, size_t ws_size,
                              hipStream_t stream)
{
    const float* x    = (const float*)d_in[0];
    const float* cond = (const float*)d_in[1];
    const int*   tarr = (const int*)d_in[2];
    const float* lq_w = (const float*)d_in[3];
    const float* lq_b = (const float*)d_in[4];
    const float* lk_w = (const float*)d_in[5];
    const float* lk_b = (const float*)d_in[6];
    const float* lv_w = (const float*)d_in[7];
    const float* lv_b = (const float*)d_in[8];
    const float* lo_w = (const float*)d_in[9];
    const float* lo_b = (const float*)d_in[10];
    const float* gq_w = (const float*)d_in[11];
    const float* gq_b = (const float*)d_in[12];
    const float* gk_w = (const float*)d_in[13];
    const float* gk_b = (const float*)d_in[14];
    const float* gv_w = (const float*)d_in[15];
    const float* gv_b = (const float*)d_in[16];
    const float* go_w = (const float*)d_in[17];
    const float* go_b = (const float*)d_in[18];
    float* out = (float*)d_out;

    const size_t N = (size_t)BB * CC * TT;
    char* w = (char*)d_ws;
    ushort* xtb = (ushort*)w; w += N * 2;
    ushort* ctb = (ushort*)w; w += N * 2;
    ushort* lq  = (ushort*)w; w += N * 2;
    ushort* lk  = (ushort*)w; w += N * 2;
    ushort* lv  = (ushort*)w; w += N * 2;
    ushort* gqb = (ushort*)w; w += N * 2;
    ushort* ktb = (ushort*)w; w += N * 2;     // fragment-tiled K
    ushort* vtb = (ushort*)w; w += N * 2;     // fragment-tiled V
    ushort* scr = (ushort*)w; w += N * 2;
    ushort* AG  = (ushort*)w; w += (size_t)BB * TT * 1024 * 2;
    ushort* wbf = (ushort*)w; w += (size_t)6 * 512 * 512 * 2;
    ushort* wc  = (ushort*)w; w += (size_t)512 * 1024 * 2;
    float* ctab = (float*)w;  w += (size_t)32 * 2048 * 4;
    float* stab = (float*)w;

    dim3 blk(256);

    prep_kernel<<<dim3(4352), blk, 0, stream>>>(x, cond,
                                                lq_w, lk_w, lv_w, gq_w, gk_w, gv_w, lo_w, go_w,
                                                wbf, wc, xtb, ctb, ctab, stab);

    gemm6_kernel<<<dim3(64, 4, 6), dim3(512), 0, stream>>>(wbf, lq_b, lk_b, lv_b, gq_b, gk_b, gv_b,
                                                           xtb, ctb, lq, lk, lv, gqb, ktb, vtb, ctab, stab);

    local_attn_kernel<<<dim3(BB * HH * TT / 256), blk, 0, stream>>>(lq, lk, lv, scr, tarr);
    transpose_bf16_kernel<<<dim3(32, 8, BB), blk, 0, stream>>>(scr, AG);

    flash_global_kernel<<<dim3(512), dim3(512), 0, stream>>>(gqb, ktb, vtb, AG, tarr);

    gemm_comb_kernel<<<dim3(128, 4), blk, 0, stream>>>(wc, lo_b, go_b, AG, out, tarr);
}

// Round 19
// 154.871 us; speedup vs baseline: 1.6028x; 1.0678x over previous
//
#include <hip/hip_runtime.h>
#include <math.h>

#define BB 4
#define CC 512
#define TT 2048
#define HH 8
#define DD 64

static constexpr float SCALE = 0.125f;                 // D^-0.5
static constexpr float QK_SCALE_LOG2 = 0.125f * 1.4426950408889634f;  // fold log2(e): softmax in exp2 domain

typedef __attribute__((ext_vector_type(8)))  short  short8;
typedef __attribute__((ext_vector_type(4)))  float  f32x4;
typedef __attribute__((ext_vector_type(16))) float  f32x16;
typedef __attribute__((ext_vector_type(2)))  unsigned int u32x2;

static __device__ __forceinline__ ushort f2bf(float f) {
    uint u = __float_as_uint(f);
    uint r = (u + 0x7fffu + ((u >> 16) & 1u)) >> 16;
    return (ushort)r;
}
static __device__ __forceinline__ float bf2f(ushort u) {
    return __uint_as_float((uint)u << 16);
}

typedef unsigned int u32;
typedef u32 __attribute__((address_space(1))) gu32;
typedef u32 __attribute__((address_space(3))) lu32;
static __device__ __forceinline__ void gload_lds16(const void* g, void* l) {
    __builtin_amdgcn_global_load_lds((const gu32*)g, (lu32*)l, 16, 0, 0);
}

// ======================= fused prep: rope table + weight cvt + input transpose =======================
__global__ __launch_bounds__(256)
void prep_kernel(const float* __restrict__ x, const float* __restrict__ cond,
                 const float* w0, const float* w1, const float* w2, const float* w3,
                 const float* w4, const float* w5, const float* w6, const float* w7,
                 ushort* __restrict__ wbf, ushort* __restrict__ wc,
                 ushort* __restrict__ xtb, ushort* __restrict__ ctb,
                 float* __restrict__ ctab, float* __restrict__ stab)
{
    __shared__ ushort L[64][66];
    int bid = blockIdx.x;
    const int tid = threadIdx.x;

    if (bid < 256) {                       // ---- rope table ----
        int idx = bid * 256 + tid;         // 64K threads: [i][t]
        int i = idx >> 11;
        int t = idx & 2047;
        float ex   = (2.0f * (float)i) / 64.0f;
        float invf = powf(10000.0f, -ex);
        float ang  = (float)t * invf;
        ctab[idx] = cosf(ang);
        stab[idx] = sinf(ang);
        return;
    }
    bid -= 256;
    if (bid < 2048) {                      // ---- weight fp32 -> bf16 ----
        const float* srcs[8] = {w0, w1, w2, w3, w4, w5, w6, w7};
        int wi = bid >> 8;
        int idx = ((bid & 255) * 256 + tid) * 4;
        float4 v = *(const float4*)&srcs[wi][idx];
        uint lo = (uint)f2bf(v.x) | ((uint)f2bf(v.y) << 16);
        uint hi = (uint)f2bf(v.z) | ((uint)f2bf(v.w) << 16);
        uint2 pk = make_uint2(lo, hi);
        if (wi < 6) {
            *(uint2*)&wbf[(size_t)wi * 262144 + idx] = pk;
        } else {
            int row = idx >> 9, col = idx & 511;
            *(uint2*)&wc[(size_t)row * 1024 + (wi - 6) * 512 + col] = pk;
        }
        return;
    }
    bid -= 2048;                           // ---- transpose [b][c][t] -> bf16 [b][t][c] ----
    const int z = bid >> 8;                // 0..7
    const int r = bid & 255;
    const float* in = (z < 4) ? x : cond;
    ushort* outp    = (z < 4) ? xtb : ctb;
    const int b = z & 3;
    const int t0 = (r & 31) * 64, c0 = (r >> 5) * 64;
    const float* inb = in + (size_t)b * CC * TT;
    ushort* outb = outp + (size_t)b * TT * CC;
    const int lc = tid >> 6;
    const int lt = tid & 63;
    #pragma unroll
    for (int i = 0; i < 16; i++) {
        int c = i * 4 + lc;
        L[c][lt] = f2bf(inb[(size_t)(c0 + c) * TT + t0 + lt]);
    }
    __syncthreads();
    #pragma unroll
    for (int i = 0; i < 16; i++) {
        int t = i * 4 + lc;
        outb[(size_t)(t0 + t) * CC + c0 + lt] = L[lt][t];
    }
}

// ---- scrambled local-attn output [b][c][t] -> AG[b][t][0..512) (row stride 1024) ----
__global__ __launch_bounds__(256)
void transpose_bf16_kernel(const ushort* __restrict__ in, ushort* __restrict__ AG)
{
    __shared__ ushort L[64][66];
    const int t0 = blockIdx.x * 64, c0 = blockIdx.y * 64, b = blockIdx.z;
    const ushort* inb = in + (size_t)b * CC * TT;
    ushort* outb = AG + (size_t)b * TT * 1024;
    const int lc = threadIdx.x >> 6;
    const int lt = threadIdx.x & 63;
    #pragma unroll
    for (int i = 0; i < 16; i++) {
        int c = i * 4 + lc;
        L[c][lt] = inb[(size_t)(c0 + c) * TT + t0 + lt];
    }
    __syncthreads();
    #pragma unroll
    for (int i = 0; i < 16; i++) {
        int t = i * 4 + lc;
        outb[(size_t)(t0 + t) * 1024 + c0 + lt] = L[lt][t];
    }
}

// ======================= MFMA GEMM core (macro used by gemm_comb only) =======================
#define GEMM_BODY(Wp, XTp, KD, NB)                                                  \
    __shared__ __align__(16) ushort As[2][128][32];                                 \
    __shared__ __align__(16) ushort Bs[2][NB][32];                                  \
    const int tid  = threadIdx.x;                                                   \
    const int wid  = tid >> 6;                                                      \
    const int lane = tid & 63;                                                      \
    const int x  = lane & 15;                                                       \
    const int gq = lane >> 4;                                                       \
    const int wm = wid >> 1, wn = wid & 1;                                          \
    const int m0 = blockIdx.y * 128;                                                \
    const int n0 = blockIdx.x * NB;                                                 \
    const int srow = lane >> 2;                                                     \
    const int sblk = lane & 3;                                                      \
    f32x4 acc[4][NB / 32];                                                          \
    _Pragma("unroll")                                                               \
    for (int i = 0; i < 4; i++)                                                     \
        _Pragma("unroll")                                                           \
        for (int j = 0; j < NB / 32; j++) acc[i][j] = (f32x4){0.f, 0.f, 0.f, 0.f};  \
    auto stage = [&](int bf, int k0) {                                              \
        _Pragma("unroll")                                                           \
        for (int c = 0; c < 2; c++) {                                               \
            int row = c * 64 + wid * 16 + srow;                                     \
            int dbk = sblk ^ ((row >> 1) & 3);                                      \
            gload_lds16(&Wp[(size_t)(m0 + row) * KD + k0 + dbk * 8],                \
                        &As[bf][c * 64 + wid * 16][0]);                             \
            if (c * 64 < NB)                                                        \
                gload_lds16(&XTp[(size_t)(n0 + row) * KD + k0 + dbk * 8],           \
                            &Bs[bf][c * 64 + wid * 16][0]);                         \
        }                                                                           \
    };                                                                              \
    stage(0, 0);                                                                    \
    __syncthreads();                                                                \
    for (int ks = 0; ks < (KD) / 32; ks++) {                                        \
        int cur = ks & 1;                                                           \
        if (ks < (KD) / 32 - 1) stage(cur ^ 1, (ks + 1) * 32);                      \
        short8 aF[4], bF[NB / 32];                                                  \
        _Pragma("unroll")                                                           \
        for (int mi = 0; mi < 4; mi++) {                                            \
            int row = wm * 64 + mi * 16 + x;                                        \
            aF[mi] = *(const short8*)&As[cur][row][(gq ^ ((row >> 1) & 3)) * 8];    \
        }                                                                           \
        _Pragma("unroll")                                                           \
        for (int nj = 0; nj < NB / 32; nj++) {                                      \
            int row = wn * (NB / 2) + nj * 16 + x;                                  \
            bF[nj] = *(const short8*)&Bs[cur][row][(gq ^ ((row >> 1) & 3)) * 8];    \
        }                                                                           \
        _Pragma("unroll")                                                           \
        for (int mi = 0; mi < 4; mi++)                                              \
            _Pragma("unroll")                                                       \
            for (int nj = 0; nj < NB / 32; nj++)                                    \
                acc[mi][nj] = __builtin_amdgcn_mfma_f32_16x16x32_bf16(aF[mi], bF[nj], acc[mi][nj], 0, 0, 0); \
        __syncthreads();                                                            \
    }

// ---- all 6 qkv projections, 8-WAVE blocks (wave grid 2m x 4n; 64x32 per wave) ----
__global__ __launch_bounds__(512, 4)
void gemm6_kernel(const ushort* __restrict__ wbase,
                  const float* __restrict__ b0, const float* __restrict__ b1, const float* __restrict__ b2,
                  const float* __restrict__ b3, const float* __restrict__ b4, const float* __restrict__ b5,
                  const ushort* __restrict__ xtb, const ushort* __restrict__ ctb,
                  ushort* __restrict__ y0, ushort* __restrict__ y1, ushort* __restrict__ y2,
                  ushort* __restrict__ y3, ushort* __restrict__ y4, ushort* __restrict__ y5,
                  const float* __restrict__ ctab, const float* __restrict__ stab)
{
    __shared__ __align__(16) ushort SMEM[16384];   // As[2][128][32] | Bs[2][128][32] | bounce(128x128)
    ushort (*As)[128][32] = (ushort(*)[128][32])&SMEM[0];
    ushort (*Bs)[128][32] = (ushort(*)[128][32])&SMEM[8192];

    const int z = blockIdx.z;
    const ushort* Wp  = wbase + (size_t)z * 262144;
    const float* bias = (z == 0) ? b0 : (z == 1) ? b1 : (z == 2) ? b2 : (z == 3) ? b3 : (z == 4) ? b4 : b5;
    const ushort* XTp = (z == 0 || z == 3) ? xtb : ctb;
    ushort* Y = (z == 0) ? y0 : (z == 1) ? y1 : (z == 2) ? y2 : (z == 3) ? y3 : (z == 4) ? y4 : y5;
    const bool do_rope = (z == 3 || z == 4);
    const bool swp = (z == 5);
    const float qscale = (z == 3) ? QK_SCALE_LOG2 : 1.0f;

    const int tid  = threadIdx.x;          // 0..511
    const int wid  = tid >> 6;             // 0..7
    const int lane = tid & 63;
    const int x  = lane & 15;
    const int gq = lane >> 4;
    const int wm = wid >> 2;               // 0..1 (64 m-rows each)
    const int wn = wid & 3;                // 0..3 (32 n-rows each)
    const int m0 = blockIdx.y * 128;
    const int n0 = blockIdx.x * 128;
    const int srow = lane >> 2;
    const int sblk = lane & 3;

    f32x4 acc[4][2];
    #pragma unroll
    for (int i = 0; i < 4; i++)
        #pragma unroll
        for (int j = 0; j < 2; j++) acc[i][j] = (f32x4){0.f, 0.f, 0.f, 0.f};

    auto stage = [&](int bf, int k0) {
        int row = wid * 16 + srow;                     // 0..127
        int dbk = sblk ^ ((row >> 1) & 3);
        gload_lds16(&Wp[(size_t)(m0 + row) * 512 + k0 + dbk * 8],
                    &As[bf][wid * 16][0]);
        gload_lds16(&XTp[(size_t)(n0 + row) * 512 + k0 + dbk * 8],
                    &Bs[bf][wid * 16][0]);
    };
    stage(0, 0);
    __syncthreads();

    for (int ks = 0; ks < 16; ks++) {
        int cur = ks & 1;
        if (ks < 15) stage(cur ^ 1, (ks + 1) * 32);
        short8 aF[4], bF[2];
        #pragma unroll
        for (int mi = 0; mi < 4; mi++) {
            int row = wm * 64 + mi * 16 + x;
            aF[mi] = *(const short8*)&As[cur][row][(gq ^ ((row >> 1) & 3)) * 8];
        }
        #pragma unroll
        for (int nj = 0; nj < 2; nj++) {
            int row = wn * 32 + nj * 16 + x;
            bF[nj] = *(const short8*)&Bs[cur][row][(gq ^ ((row >> 1) & 3)) * 8];
        }
        if (swp) {
            #pragma unroll
            for (int mi = 0; mi < 4; mi++)
                #pragma unroll
                for (int nj = 0; nj < 2; nj++)
                    acc[mi][nj] = __builtin_amdgcn_mfma_f32_16x16x32_bf16(bF[nj], aF[mi], acc[mi][nj], 0, 0, 0);
        } else {
            #pragma unroll
            for (int mi = 0; mi < 4; mi++)
                #pragma unroll
                for (int nj = 0; nj < 2; nj++)
                    acc[mi][nj] = __builtin_amdgcn_mfma_f32_16x16x32_bf16(aF[mi], bF[nj], acc[mi][nj], 0, 0, 0);
        }
        __syncthreads();
    }

    // ---- bounce write: bias (+rope), pack 4 bf16 -> 8B into swizzled 128x128 tile ----
    if (!swp) {
        #pragma unroll
        for (int mi = 0; mi < 4; mi++) {
            const int cL = wm * 64 + mi * 16 + 4 * gq;
            const int mb = m0 + cL;
            float bv[4];
            #pragma unroll
            for (int r = 0; r < 4; r++) bv[r] = bias[mb + r];
            #pragma unroll
            for (int nj = 0; nj < 2; nj++) {
                const int tL = wn * 32 + nj * 16 + x;
                const int tt = (n0 + tL) & 2047;
                f32x4 v = acc[mi][nj];
                v[0] += bv[0]; v[1] += bv[1]; v[2] += bv[2]; v[3] += bv[3];
                if (do_rope) {
                    const int i0 = (mb & 63) >> 1;
                    float c0 = ctab[(size_t)i0 * 2048 + tt],       s0 = stab[(size_t)i0 * 2048 + tt];
                    float c1 = ctab[(size_t)(i0 + 1) * 2048 + tt], s1 = stab[(size_t)(i0 + 1) * 2048 + tt];
                    float e0 = (v[0] * c0 - v[1] * s0) * qscale;
                    float e1 = (v[0] * s0 + v[1] * c0) * qscale;
                    float e2 = (v[2] * c1 - v[3] * s1) * qscale;
                    float e3 = (v[2] * s1 + v[3] * c1) * qscale;
                    v[0] = e0; v[1] = e1; v[2] = e2; v[3] = e3;
                }
                uint lo = (uint)f2bf(v[0]) | ((uint)f2bf(v[1]) << 16);
                uint hi = (uint)f2bf(v[2]) | ((uint)f2bf(v[3]) << 16);
                const int blk = (cL >> 3) ^ (tL & 7);
                *(uint2*)&SMEM[tL * 128 + blk * 8 + (gq & 1) * 4] = make_uint2(lo, hi);
            }
        }
    } else {
        #pragma unroll
        for (int mi = 0; mi < 4; mi++) {
            const int cL = wm * 64 + mi * 16 + x;
            const float bv = bias[m0 + cL];
            #pragma unroll
            for (int nj = 0; nj < 2; nj++) {
                const int tL = wn * 32 + nj * 16 + 4 * gq;
                f32x4 v = acc[mi][nj];
                uint lo = (uint)f2bf(v[0] + bv) | ((uint)f2bf(v[1] + bv) << 16);
                uint hi = (uint)f2bf(v[2] + bv) | ((uint)f2bf(v[3] + bv) << 16);
                const int blk = (tL >> 3) ^ (cL & 7);
                *(uint2*)&SMEM[cL * 128 + blk * 8 + (gq & 1) * 4] = make_uint2(lo, hi);
            }
        }
    }
    __syncthreads();

    // ---- coalesced global stores (16B/thread, 4 sweeps of 512 threads) ----
    if (z <= 3) {
        #pragma unroll
        for (int s = 0; s < 4; s++) {
            const int chunk = s * 512 + tid;
            const int row = chunk >> 4;       // t
            const int blk = chunk & 15;       // c-block
            uint4 val = *(const uint4*)&SMEM[row * 128 + ((blk ^ (row & 7)) << 3)];
            *(uint4*)&Y[(size_t)(n0 + row) * 512 + m0 + blk * 8] = val;
        }
    } else if (z == 4) {
        const int bidx = n0 >> 11;
        #pragma unroll
        for (int s = 0; s < 4; s++) {
            const int chunk = s * 512 + tid;
            const int row = chunk & 127;      // t
            const int blk = chunk >> 7;       // c-block
            uint4 val = *(const uint4*)&SMEM[row * 128 + ((blk ^ (row & 7)) << 3)];
            const int tt = (n0 + row) & 2047;
            const int kt = tt >> 6, tk = tt & 63, sb = tk >> 5, qh = tk & 31;
            const int c = m0 + blk * 8;
            const int hh = (c >> 6) & 7, d = c & 63;
            const int kap = d >> 4, hb = (d >> 3) & 1;
            size_t off = (size_t)(bidx * 8 + hh) * 131072
                       + (size_t)(((((kt * 2 + sb) * 4 + kap) * 2 + hb) * 32 + qh) * 8);
            *(uint4*)&Y[off] = val;
        }
    } else {
        const int bidx = n0 >> 11;
        #pragma unroll
        for (int s = 0; s < 4; s++) {
            const int chunk = s * 512 + tid;
            const int rowc = chunk & 127;     // c
            const int blk = chunk >> 7;       // t-block
            uint4 val = *(const uint4*)&SMEM[rowc * 128 + ((blk ^ (rowc & 7)) << 3)];
            const int c = m0 + rowc;
            const int hh = (c >> 6) & 7, d = c & 63;
            const int qh = d & 31, db = (d >> 5) & 1;
            const int tt0 = (n0 + blk * 8) & 2047;
            const int kt = tt0 >> 6, kk = tt0 & 63;
            const int kc = kk >> 4, hb = (kk >> 3) & 1;
            size_t off = (size_t)(bidx * 8 + hh) * 131072
                       + (size_t)(((((kt * 2 + db) * 4 + kc) * 2 + hb) * 32 + qh) * 8);
            *(uint4*)&Y[off] = val;
        }
    }
}

// ---- combined output projection (NB=64): d_out = Wc[512][1024].AG[n][1024] + mixed bias ----
__global__ __launch_bounds__(256)
void gemm_comb_kernel(const ushort* __restrict__ Wp,
                      const float* __restrict__ bl, const float* __restrict__ bg,
                      const ushort* __restrict__ XTp, float* __restrict__ Y,
                      const int* __restrict__ tarr)
{
    GEMM_BODY(Wp, XTp, 1024, 64)

    const int bidx = (n0 + wn * 32) >> 11;
    float tn = (float)tarr[bidx] / 999.0f;
    float sl = sqrtf(tn), sg = sqrtf(1.0f - tn);

    #pragma unroll
    for (int mi = 0; mi < 4; mi++) {
        const int mb = m0 + wm * 64 + mi * 16 + 4 * gq;
        float bv[4];
        #pragma unroll
        for (int r = 0; r < 4; r++) bv[r] = sl * bl[mb + r] + sg * bg[mb + r];
        #pragma unroll
        for (int nj = 0; nj < 2; nj++) {
            const int tt = (n0 + wn * 32 + nj * 16 + x) & 2047;
            f32x4 v = acc[mi][nj];
            #pragma unroll
            for (int r = 0; r < 4; r++)
                Y[((size_t)bidx * 512 + mb + r) * 2048 + tt] = v[r] + bv[r];
        }
    }
}

// ======================= local windowed attention (4-way d-split, bf16 [t][c] in) =======================
// Lane = (qu = lane>>4)*16 + tl: 4 threads per t, each owns d-quarter [16*qu, 16*qu+16).
// Partial dots over 16 d; full dot via shfl_xor(16) + shfl_xor(32) (all quarters of a t
// share one wave). Softmax recomputed per quarter (identical); PV + store over own 16 d.
// 262144 threads = 1024 blocks -> 4 waves/SIMD (was 1: grid-capped at 256 blocks).
__global__ __launch_bounds__(256)
void local_attn_kernel(const ushort* __restrict__ qt, const ushort* __restrict__ kt,
                       const ushort* __restrict__ vt, ushort* __restrict__ outb,
                       const int* __restrict__ tarr)
{
    const int gidx = blockIdx.x * 256 + threadIdx.x;
    const int lane = threadIdx.x & 63;
    const int qu = lane >> 4;              // d-quarter
    const int wv = gidx >> 6;              // wave id: 16 consecutive t of one (b,h)
    const int lin = wv * 16 + (lane & 15); // linear (b,h,t)
    const int t = lin & (TT - 1);
    const int h = (lin >> 11) & (HH - 1);
    const int b = lin >> 14;
    const size_t rb = (size_t)b * TT;
    const int co = h * DD + qu * 16;
    const float wl = sqrtf((float)tarr[b] / 999.0f);

    float qf[16];
    {
        const ushort* qp = qt + (rb + t) * 512 + co;
        #pragma unroll
        for (int i = 0; i < 2; i++) {
            short8 v = *(const short8*)&qp[i * 8];
            #pragma unroll
            for (int j = 0; j < 8; j++) qf[i * 8 + j] = bf2f((ushort)v[j]);
        }
    }

    int koff[16]; float msk[16];
    #pragma unroll
    for (int w = 0; w < 16; w++) {
        int kidx = t + w - 8;
        msk[w]  = (kidx >= 0 && kidx < TT) ? 1.0f : 0.0f;
        koff[w] = min(max(kidx, 0), TT - 1);
    }

    float dots[16];
    #pragma unroll
    for (int w = 0; w < 16; w++) {
        const ushort* kp = kt + (rb + koff[w]) * 512 + co;
        float d0 = 0.f, d1 = 0.f;
        #pragma unroll
        for (int i = 0; i < 2; i++) {
            short8 v = *(const short8*)&kp[i * 8];
            #pragma unroll
            for (int j = 0; j < 8; j += 2) {
                d0 = fmaf(qf[i * 8 + j],     bf2f((ushort)v[j]),     d0);
                d1 = fmaf(qf[i * 8 + j + 1], bf2f((ushort)v[j + 1]), d1);
            }
        }
        dots[w] = d0 + d1;
    }
    // reduce partial dots across the 4 quarters (lanes qu^1, qu^2)
    #pragma unroll
    for (int w = 0; w < 16; w++) {
        dots[w] += __shfl_xor(dots[w], 16);
        dots[w] += __shfl_xor(dots[w], 32);
    }

    float m = -1e30f;
    #pragma unroll
    for (int w = 0; w < 16; w++) { dots[w] = dots[w] * SCALE * msk[w]; m = fmaxf(m, dots[w]); }
    float p[16], s = 0.f;
    #pragma unroll
    for (int w = 0; w < 16; w++) { p[w] = __expf(dots[w] - m); s += p[w]; }
    float inv = wl / s;
    #pragma unroll
    for (int w = 0; w < 16; w++) p[w] *= msk[w] * inv;

    float oa[16];
    #pragma unroll
    for (int d = 0; d < 16; d++) oa[d] = 0.f;
    #pragma unroll
    for (int w = 0; w < 16; w++) {
        const ushort* vp = vt + (rb + koff[w]) * 512 + co;
        #pragma unroll
        for (int i = 0; i < 2; i++) {
            short8 v = *(const short8*)&vp[i * 8];
            #pragma unroll
            for (int j = 0; j < 8; j++)
                oa[i * 8 + j] = fmaf(p[w], bf2f((ushort)v[j]), oa[i * 8 + j]);
        }
    }

    // scrambled store: channel h*64 + t/32, position (t%32)*64 + d (own 16-d quarter)
    ushort* op = outb + ((size_t)b * CC + h * DD + (t >> 5)) * TT + (size_t)(t & 31) * DD + qu * 16;
    #pragma unroll
    for (int i = 0; i < 2; i++) {
        uint w0 = (uint)f2bf(oa[i * 8 + 0]) | ((uint)f2bf(oa[i * 8 + 1]) << 16);
        uint w1 = (uint)f2bf(oa[i * 8 + 2]) | ((uint)f2bf(oa[i * 8 + 3]) << 16);
        uint w2 = (uint)f2bf(oa[i * 8 + 4]) | ((uint)f2bf(oa[i * 8 + 5]) << 16);
        uint w3 = (uint)f2bf(oa[i * 8 + 6]) | ((uint)f2bf(oa[i * 8 + 7]) << 16);
        *(uint4*)&op[i * 8] = make_uint4(w0, w1, w2, w3);
    }
}

// ======================= global flash attention (in-block K-split x2, 8 waves, LDS combine) =======================
__global__ __launch_bounds__(512)
void flash_global_kernel(const ushort* __restrict__ qtd, const ushort* __restrict__ KT,
                         const ushort* __restrict__ VT, ushort* __restrict__ AG,
                         const int* __restrict__ tarr)
{
    __shared__ __align__(16) ushort Ks[2][2][4096];   // [grp][dbuf]
    __shared__ __align__(16) ushort Vs[2][2][4096];

    const int tid  = threadIdx.x;
    const int grp  = tid >> 8;          // K-half group (wave-uniform)
    const int t8   = tid & 255;
    const int w    = t8 >> 6;           // wave-in-group 0..3
    const int lane = tid & 63;
    const int qh   = lane & 31;
    const int h    = lane >> 5;

    const int bid = blockIdx.x;
    const int sw  = (bid & 7) * 64 + (bid >> 3);
    const int qt  = sw & 15;            // q-tile of 128
    const int p   = sw >> 4;            // b*8+hh
    const int hh  = p & 7, b = p >> 3;

    const size_t kvbase = (size_t)p * 131072 + (size_t)grp * (16 * 4096);
    const size_t btd    = (size_t)b * TT;
    const int q_glob = qt * 128 + w * 32 + qh;
    const float sg_mix = sqrtf(1.0f - (float)tarr[b] / 999.0f);

    short8 aQ[4];
    {
        const ushort* qrow = qtd + (btd + q_glob) * 512 + hh * 64;
        #pragma unroll
        for (int kap = 0; kap < 4; kap++)
            aQ[kap] = *(const short8*)&qrow[kap * 16 + h * 8];
    }

    f32x16 oacc[2];
    #pragma unroll
    for (int d = 0; d < 2; d++)
        #pragma unroll
        for (int r = 0; r < 16; r++) oacc[d][r] = 0.f;
    float l_run = 0.0f;

    const ushort* kA = KT + kvbase + (size_t)(2 * w) * 512 + lane * 8;
    const ushort* vA = VT + kvbase + (size_t)(2 * w) * 512 + lane * 8;

    auto issue = [&](int buf, int kt) {
        const size_t off = (size_t)kt * 4096;
        gload_lds16(kA + off,       &Ks[grp][buf][(2 * w) * 512]);
        gload_lds16(kA + off + 512, &Ks[grp][buf][(2 * w + 1) * 512]);
        gload_lds16(vA + off,       &Vs[grp][buf][(2 * w) * 512]);
        gload_lds16(vA + off + 512, &Vs[grp][buf][(2 * w + 1) * 512]);
    };
    issue(0, 0);

    int cur = 0;
    for (int kt = 0; kt < 16; kt++) {
        __syncthreads();
        if (kt < 15) issue(cur ^ 1, kt + 1);

        const ushort* KsC = &Ks[grp][cur][0];
        const ushort* VsC = &Vs[grp][cur][0];

        f32x16 ST[2];
        #pragma unroll
        for (int sb = 0; sb < 2; sb++)
            #pragma unroll
            for (int r = 0; r < 16; r++) ST[sb][r] = 0.f;
        __builtin_amdgcn_s_setprio(1);
        #pragma unroll
        for (int sb = 0; sb < 2; sb++)
            #pragma unroll
            for (int kap = 0; kap < 4; kap++) {
                short8 aK = *(const short8*)&KsC[(sb * 4 + kap) * 512 + lane * 8];
                ST[sb] = __builtin_amdgcn_mfma_f32_32x32x16_bf16(aK, aQ[kap], ST[sb], 0, 0, 0);
            }
        __builtin_amdgcn_s_setprio(0);

        float s0 = 0.f, s1 = 0.f, s2 = 0.f, s3 = 0.f;
        #pragma unroll
        for (int sb = 0; sb < 2; sb++)
            #pragma unroll
            for (int r = 0; r < 16; r += 4) {
                ST[sb][r + 0] = __builtin_amdgcn_exp2f(ST[sb][r + 0]);
                ST[sb][r + 1] = __builtin_amdgcn_exp2f(ST[sb][r + 1]);
                ST[sb][r + 2] = __builtin_amdgcn_exp2f(ST[sb][r + 2]);
                ST[sb][r + 3] = __builtin_amdgcn_exp2f(ST[sb][r + 3]);
                s0 += ST[sb][r + 0]; s1 += ST[sb][r + 1];
                s2 += ST[sb][r + 2]; s3 += ST[sb][r + 3];
            }
        l_run += (s0 + s1) + (s2 + s3);

        short8 bP[4];
        #pragma unroll
        for (int sb = 0; sb < 2; sb++)
            #pragma unroll
            for (int kcp = 0; kcp < 2; kcp++) {
                const int rb2 = kcp * 8;
                uint ca, cb, cc, cd;
                asm("v_cvt_pk_bf16_f32 %0, %1, %2" : "=v"(ca) : "v"(ST[sb][rb2 + 0]), "v"(ST[sb][rb2 + 1]));
                asm("v_cvt_pk_bf16_f32 %0, %1, %2" : "=v"(cb) : "v"(ST[sb][rb2 + 2]), "v"(ST[sb][rb2 + 3]));
                asm("v_cvt_pk_bf16_f32 %0, %1, %2" : "=v"(cc) : "v"(ST[sb][rb2 + 4]), "v"(ST[sb][rb2 + 5]));
                asm("v_cvt_pk_bf16_f32 %0, %1, %2" : "=v"(cd) : "v"(ST[sb][rb2 + 6]), "v"(ST[sb][rb2 + 7]));
                u32x2 r1 = __builtin_amdgcn_permlane32_swap(ca, cc, false, false);
                u32x2 r2 = __builtin_amdgcn_permlane32_swap(cb, cd, false, false);
                uint4 bu = make_uint4(r1[0], r2[0], r1[1], r2[1]);
                bP[sb * 2 + kcp] = __builtin_bit_cast(short8, bu);
            }

        __builtin_amdgcn_s_setprio(1);
        #pragma unroll
        for (int db = 0; db < 2; db++)
            #pragma unroll
            for (int kc = 0; kc < 4; kc++) {
                short8 aV = *(const short8*)&VsC[(db * 4 + kc) * 512 + lane * 8];
                oacc[db] = __builtin_amdgcn_mfma_f32_32x32x16_bf16(aV, bP[kc], oacc[db], 0, 0, 0);
            }
        __builtin_amdgcn_s_setprio(0);
        cur ^= 1;
    }

    // ---- in-LDS combine: group 1 -> LDS, group 0 adds & stores ----
    __syncthreads();                      // all compute done; Ks/Vs now dead
    f32x4* OP = (f32x4*)&Ks[0][0][0];     // [8][256] f32x4 = 32KB
    float* LP = (float*)&Vs[0][0][0];     // 256 floats
    if (grp == 1) {
        #pragma unroll
        for (int j = 0; j < 8; j++)
            OP[j * 256 + t8] = (f32x4){oacc[j >> 2][(j & 3) * 4 + 0], oacc[j >> 2][(j & 3) * 4 + 1],
                                       oacc[j >> 2][(j & 3) * 4 + 2], oacc[j >> 2][(j & 3) * 4 + 3]};
        LP[t8] = l_run;
    }
    __syncthreads();
    if (grp == 0) {
        #pragma unroll
        for (int j = 0; j < 8; j++) {
            f32x4 o = OP[j * 256 + t8];
            oacc[j >> 2][(j & 3) * 4 + 0] += o[0];
            oacc[j >> 2][(j & 3) * 4 + 1] += o[1];
            oacc[j >> 2][(j & 3) * 4 + 2] += o[2];
            oacc[j >> 2][(j & 3) * 4 + 3] += o[3];
        }
        l_run += LP[t8];
        float ltot = l_run + __shfl_xor(l_run, 32);
        float inv = sg_mix / ltot;
        ushort* agrow = AG + (btd + q_glob) * 1024 + 512 + hh * 64;
        #pragma unroll
        for (int db = 0; db < 2; db++)
            #pragma unroll
            for (int rq = 0; rq < 4; rq++) {
                const int d0 = db * 32 + rq * 8 + h * 4;
                uint lo = (uint)f2bf(oacc[db][rq * 4 + 0] * inv) | ((uint)f2bf(oacc[db][rq * 4 + 1] * inv) << 16);
                uint hi = (uint)f2bf(oacc[db][rq * 4 + 2] * inv) | ((uint)f2bf(oacc[db][rq * 4 + 3] * inv) << 16);
                *(uint2*)&agrow[d0] = make_uint2(lo, hi);
            }
    }
}

// ======================= launch =======================
extern "C" void kernel_launch(void* const* d_in, const int* in_sizes, int n_in,
                              void* d_out, int out_size, void* d_ws, size_t ws_size,
                              hipStream_t stream)
{
    const float* x    = (const float*)d_in[0];
    const float* cond = (const float*)d_in[1];
    const int*   tarr = (const int*)d_in[2];
    const float* lq_w = (const float*)d_in[3];
    const float* lq_b = (const float*)d_in[4];
    const float* lk_w = (const float*)d_in[5];
    const float* lk_b = (const float*)d_in[6];
    const float* lv_w = (const float*)d_in[7];
    const float* lv_b = (const float*)d_in[8];
    const float* lo_w = (const float*)d_in[9];
    const float* lo_b = (const float*)d_in[10];
    const float* gq_w = (const float*)d_in[11];
    const float* gq_b = (const float*)d_in[12];
    const float* gk_w = (const float*)d_in[13];
    const float* gk_b = (const float*)d_in[14];
    const float* gv_w = (const float*)d_in[15];
    const float* gv_b = (const float*)d_in[16];
    const float* go_w = (const float*)d_in[17];
    const float* go_b = (const float*)d_in[18];
    float* out = (float*)d_out;

    const size_t N = (size_t)BB * CC * TT;
    char* w = (char*)d_ws;
    ushort* xtb = (ushort*)w; w += N * 2;
    ushort* ctb = (ushort*)w; w += N * 2;
    ushort* lq  = (ushort*)w; w += N * 2;
    ushort* lk  = (ushort*)w; w += N * 2;
    ushort* lv  = (ushort*)w; w += N * 2;
    ushort* gqb = (ushort*)w; w += N * 2;
    ushort* ktb = (ushort*)w; w += N * 2;     // fragment-tiled K
    ushort* vtb = (ushort*)w; w += N * 2;     // fragment-tiled V
    ushort* scr = (ushort*)w; w += N * 2;
    ushort* AG  = (ushort*)w; w += (size_t)BB * TT * 1024 * 2;
    ushort* wbf = (ushort*)w; w += (size_t)6 * 512 * 512 * 2;
    ushort* wc  = (ushort*)w; w += (size_t)512 * 1024 * 2;
    float* ctab = (float*)w;  w += (size_t)32 * 2048 * 4;
    float* stab = (float*)w;

    dim3 blk(256);

    prep_kernel<<<dim3(4352), blk, 0, stream>>>(x, cond,
                                                lq_w, lk_w, lv_w, gq_w, gk_w, gv_w, lo_w, go_w,
                                                wbf, wc, xtb, ctb, ctab, stab);

    gemm6_kernel<<<dim3(64, 4, 6), dim3(512), 0, stream>>>(wbf, lq_b, lk_b, lv_b, gq_b, gk_b, gv_b,
                                                           xtb, ctb, lq, lk, lv, gqb, ktb, vtb, ctab, stab);

    local_attn_kernel<<<dim3(BB * HH * TT * 4 / 256), blk, 0, stream>>>(lq, lk, lv, scr, tarr);
    transpose_bf16_kernel<<<dim3(32, 8, BB), blk, 0, stream>>>(scr, AG);

    flash_global_kernel<<<dim3(512), dim3(512), 0, stream>>>(gqb, ktb, vtb, AG, tarr);

    gemm_comb_kernel<<<dim3(128, 4), blk, 0, stream>>>(wc, lo_b, go_b, AG, out, tarr);
}